// Round 10
// baseline (739.528 us; speedup 1.0000x reference)
//
#include <hip/hip_runtime.h>

#define NN 20000
#define NE 320000

using f32x4  = __attribute__((ext_vector_type(4))) float;
using bf16x8 = __attribute__((ext_vector_type(8))) short;

__device__ __forceinline__ float bf2f(unsigned short u){
  return __uint_as_float(((unsigned int)u) << 16);
}
__device__ __forceinline__ unsigned short f2bf(float f){
  unsigned int x = __float_as_uint(f);
  unsigned int r = ((x >> 16) & 1u) + 0x7FFFu;   // RNE
  return (unsigned short)((x + r) >> 16);
}
__device__ __forceinline__ f32x4 mfma_bf16(bf16x8 a, bf16x8 b, f32x4 c){
  return __builtin_amdgcn_mfma_f32_16x16x32_bf16(a, b, c, 0, 0, 0);
}

// ---------------- weight packing into MFMA B-fragment order ----------------
__global__ __launch_bounds__(64)
void pack_w_k(const float* __restrict__ W, unsigned short* __restrict__ out,
              int N, int K, int mode){
  int lane = threadIdx.x;
  int KS = K >> 5;
  int nt = blockIdx.x / KS, ks = blockIdx.x % KS;
  int row = nt*16 + (lane & 15);
  int kb  = ks*32 + ((lane >> 4) << 3);
  size_t ob = ((size_t)(nt*KS + ks)*64 + lane)*8;
  #pragma unroll
  for(int i=0;i<8;i++){
    int k = kb + i; float f = 0.f;
    if(row < N){
      f = (mode == 0) ? W[(size_t)row*K + k]
        : (row < 256 ? W[(size_t)row*256 + k] : W[(size_t)(row-256)*256 + 128 + k]);
    }
    out[ob + i] = f2bf(f);
  }
}

// ---------------- node GEMM: C_bf16[M,N] = A' @ W^T (packed) ---------------
template<int NT, int KS, bool FUSE, bool ALPHA>
__global__ __launch_bounds__(256)
void gemm_node_k(const float* __restrict__ A, const unsigned short* __restrict__ Bp,
                 unsigned short* __restrict__ C, const float* __restrict__ sc,
                 const float* __restrict__ sh, const float* __restrict__ res,
                 const float* __restrict__ att_s, const float* __restrict__ att_d,
                 float* __restrict__ as_, float* __restrict__ ad_,
                 int M, int K, int N){
  int lane = threadIdx.x & 63, w = threadIdx.x >> 6;
  int rowbase = blockIdx.x*64 + w*16;
  int nt0 = blockIdx.y * NT;
  f32x4 acc[NT];
  #pragma unroll
  for(int i=0;i<NT;i++) acc[i] = (f32x4){0.f,0.f,0.f,0.f};
  int arow = rowbase + (lane & 15); if(arow > M-1) arow = M-1;
  const float* ap = A + (size_t)arow*K + ((lane >> 4) << 3);
  const float* rp = FUSE ? (res + (size_t)arow*K + ((lane >> 4) << 3)) : nullptr;
  const bf16x8* bp = (const bf16x8*)Bp;
  #pragma unroll
  for(int ks=0; ks<KS; ks++){
    int k0 = ks*32 + ((lane >> 4) << 3);
    f32x4 a0 = *(const f32x4*)(ap + ks*32);
    f32x4 a1 = *(const f32x4*)(ap + ks*32 + 4);
    bf16x8 af;
    if constexpr (FUSE){
      f32x4 c0 = *(const f32x4*)(sc + k0), c1 = *(const f32x4*)(sc + k0 + 4);
      f32x4 h0 = *(const f32x4*)(sh + k0), h1 = *(const f32x4*)(sh + k0 + 4);
      f32x4 r0 = *(const f32x4*)(rp + ks*32), r1 = *(const f32x4*)(rp + ks*32 + 4);
      #pragma unroll
      for(int i=0;i<4;i++){
        af[i]   = (short)f2bf(fmaxf(a0[i]*c0[i] + h0[i] + r0[i], 0.f));
        af[i+4] = (short)f2bf(fmaxf(a1[i]*c1[i] + h1[i] + r1[i], 0.f));
      }
    } else {
      #pragma unroll
      for(int i=0;i<4;i++){ af[i] = (short)f2bf(a0[i]); af[i+4] = (short)f2bf(a1[i]); }
    }
    #pragma unroll
    for(int nt=0; nt<NT; nt++)
      acc[nt] = mfma_bf16(af, bp[((size_t)(nt0+nt)*KS + ks)*64 + lane], acc[nt]);
  }
  #pragma unroll
  for(int nt=0; nt<NT; nt++){
    int col = (nt0+nt)*16 + (lane & 15);
    #pragma unroll
    for(int r=0;r<4;r++){
      int row = rowbase + ((lane >> 4) << 2) + r;
      if(row < M) C[(size_t)row*N + col] = f2bf(acc[nt][r]);
    }
  }
  if constexpr (ALPHA){
    float ps[2][4] = {{0.f,0.f,0.f,0.f},{0.f,0.f,0.f,0.f}};
    float pd[2][4] = {{0.f,0.f,0.f,0.f},{0.f,0.f,0.f,0.f}};
    #pragma unroll
    for(int nt=0; nt<NT; nt++){
      int col = (nt0+nt)*16 + (lane & 15);
      float sv = att_s[col], dv = att_d[col];
      int hh = (col >> 7) & 1;
      #pragma unroll
      for(int r=0;r<4;r++){ ps[hh][r] += acc[nt][r]*sv; pd[hh][r] += acc[nt][r]*dv; }
    }
    #pragma unroll
    for(int m=1;m<16;m<<=1){
      #pragma unroll
      for(int hh=0;hh<2;hh++){
        #pragma unroll
        for(int r=0;r<4;r++){
          ps[hh][r] += __shfl_xor(ps[hh][r], m);
          pd[hh][r] += __shfl_xor(pd[hh][r], m);
        }
      }
    }
    if((lane & 15) == 0){
      int h0 = nt0 >> 3;
      #pragma unroll
      for(int r=0;r<4;r++){
        int row = rowbase + ((lane >> 4) << 2) + r;
        if(row < M){
          #pragma unroll
          for(int hh=0;hh<2;hh++){
            as_[row*4 + h0 + hh] = ps[hh][r];
            ad_[row*4 + h0 + hh] = pd[hh][r];
          }
        }
      }
    }
  }
}

// ---------------- per-edge leaky-relu logits, written in CSR order ----------
__global__ __launch_bounds__(256)
void edge_e_k(const float* __restrict__ as_, const float* __restrict__ ad_,
              const int* __restrict__ esrc, const int* __restrict__ edst,
              const int* __restrict__ epos, float* __restrict__ ebuf){
  int e = blockIdx.x*256 + threadIdx.x; if(e >= NE) return;
  f32x4 a = *(const f32x4*)(as_ + (size_t)esrc[e]*4);
  f32x4 b = *(const f32x4*)(ad_ + (size_t)edst[e]*4);
  f32x4 v;
  #pragma unroll
  for(int h=0;h<4;h++){ float t = a[h] + b[h]; v[h] = t > 0.f ? t : 0.2f*t; }
  *(f32x4*)(ebuf + (size_t)epos[e]*4) = v;
}

// ---------------- CSR build --------------------------------------------------
__global__ __launch_bounds__(256)
void hist_k(const int* __restrict__ edst, int* __restrict__ cnt){
  int e = blockIdx.x*256 + threadIdx.x; if(e >= NE) return;
  atomicAdd(&cnt[edst[e]], 1);
}
__global__ __launch_bounds__(1024)
void scan_k(const int* __restrict__ cnt, int* __restrict__ rowp, int n){
  __shared__ int part[1024];
  int t = threadIdx.x, base = t*20;
  int s = 0;
  for(int j=0;j<20;j++) if(base+j < n) s += cnt[base+j];
  part[t] = s;
  for(int off=1; off<1024; off<<=1){
    __syncthreads();
    int u = (t >= off) ? part[t-off] : 0;
    __syncthreads();
    part[t] += u;
  }
  __syncthreads();
  int run = part[t] - s;
  for(int j=0;j<20;j++){ int idx = base+j; if(idx < n){ rowp[idx] = run; run += cnt[idx]; } }
  if(t == 1023) rowp[n] = part[1023];
}
__global__ __launch_bounds__(256)
void scatter_k(const int* __restrict__ esrc, const int* __restrict__ edst,
               const int* __restrict__ rowp, int* __restrict__ cnt2,
               int* __restrict__ eids, int* __restrict__ esrc_csr,
               int* __restrict__ edst_csr, int* __restrict__ epos){
  int e = blockIdx.x*256 + threadIdx.x; if(e >= NE) return;
  int d = edst[e];
  int pos = atomicAdd(&cnt2[d], 1);
  int j = rowp[d] + pos;
  eids[j] = e;
  esrc_csr[j] = esrc[e];
  edst_csr[j] = d;
  epos[e] = j;
}

// ---------------- GAT aggregate: wave/node, online softmax, 8-deep gather ---
__global__ __launch_bounds__(256)
void gat_aggregate_k(const unsigned short* __restrict__ hbuf, const float* __restrict__ ebuf,
                     const int* __restrict__ rowp, const int* __restrict__ esrc_csr,
                     const float* __restrict__ bias, float* __restrict__ outn, int nN){
  int lane = threadIdx.x & 63, w = threadIdx.x >> 6;
  int node = blockIdx.x*4 + w; if(node >= nN) return;
  int start = rowp[node], end = rowp[node+1];
  int h = lane >> 4, jl = lane & 15;
  // single-pass online max/sum over this head's logits (16 lanes per head)
  float m = -1e30f, s = 0.f;
  for(int j = start + jl; j < end; j += 16){
    float e = ebuf[(size_t)j*4 + h];
    float mn = fmaxf(m, e);
    s = s*expf(m - mn) + expf(e - mn);
    m = mn;
  }
  #pragma unroll
  for(int msk=1; msk<16; msk<<=1){
    float mo = __shfl_xor(m, msk), so = __shfl_xor(s, msk);
    float mn = fmaxf(m, mo);
    s = s*expf(m - mn) + so*expf(mo - mn);
    m = mn;
  }
  float inv = 1.f/(s + 1e-16f);
  float acc[8] = {0.f,0.f,0.f,0.f,0.f,0.f,0.f,0.f};
  int j = start;
  for(; j + 8 <= end; j += 8){
    int si[8]; float ev[8]; bf16x8 v[8];
    #pragma unroll
    for(int u=0;u<8;u++){ si[u] = esrc_csr[j+u]; ev[u] = ebuf[(size_t)(j+u)*4 + h]; }
    #pragma unroll
    for(int u=0;u<8;u++) v[u] = *(const bf16x8*)(hbuf + (size_t)si[u]*512 + lane*8);
    #pragma unroll
    for(int u=0;u<8;u++){
      float a = expf(ev[u] - m)*inv;
      #pragma unroll
      for(int i=0;i<8;i++) acc[i] += a*bf2f((unsigned short)v[u][i]);
    }
  }
  for(; j < end; j++){
    int sa = esrc_csr[j];
    float aa = expf(ebuf[(size_t)j*4 + h] - m)*inv;
    bf16x8 va = *(const bf16x8*)(hbuf + (size_t)sa*512 + lane*8);
    #pragma unroll
    for(int i=0;i<8;i++) acc[i] += aa*bf2f((unsigned short)va[i]);
  }
  #pragma unroll
  for(int i=0;i<8;i++){ acc[i] += __shfl_xor(acc[i], 16); acc[i] += __shfl_xor(acc[i], 32); }
  if(lane < 16){
    #pragma unroll
    for(int i=0;i<8;i++)
      outn[(size_t)node*128 + lane*8 + i] = acc[i]*0.25f + bias[lane*8 + i];
  }
}

// ---------------- BN over nodes (128 ch), float4-vectorized -----------------
__global__ __launch_bounds__(256)
void bn_stats_k(const float* __restrict__ X, float* __restrict__ sum,
                float* __restrict__ sq, int M){
  int cg = threadIdx.x & 31, rg = threadIdx.x >> 5;   // 32 col-groups x 8 row-groups
  f32x4 s = {0.f,0.f,0.f,0.f}, q = {0.f,0.f,0.f,0.f};
  for(int r = blockIdx.x*8 + rg; r < M; r += 2048){
    f32x4 v = *(const f32x4*)(X + (size_t)r*128 + cg*4);
    s += v; q += v*v;
  }
  __shared__ f32x4 S[256], Q[256];
  S[threadIdx.x] = s; Q[threadIdx.x] = q; __syncthreads();
  if(rg == 0){
    f32x4 ts = {0.f,0.f,0.f,0.f}, tq = {0.f,0.f,0.f,0.f};
    #pragma unroll
    for(int g=0; g<8; g++){ ts += S[g*32+cg]; tq += Q[g*32+cg]; }
    #pragma unroll
    for(int k=0;k<4;k++){ atomicAdd(&sum[cg*4+k], ts[k]); atomicAdd(&sq[cg*4+k], tq[k]); }
  }
}

__global__ __launch_bounds__(256)
void bn_finalize_k(const float* __restrict__ sum, const float* __restrict__ sq, float count,
                   const float* __restrict__ wbn, const float* __restrict__ bbn,
                   const float* __restrict__ badd, float* __restrict__ A,
                   float* __restrict__ B, int C){
  int c = blockIdx.x*256 + threadIdx.x; if(c >= C) return;
  float mu = sum[c]/count;
  float var = sq[c]/count - mu*mu;
  float a = rsqrtf(var + 1e-5f) * wbn[c];
  float ba = badd ? badd[c] : 0.f;
  A[c] = a; B[c] = (ba - mu)*a + bbn[c];
}

template<bool RES>
__global__ __launch_bounds__(256)
void bn_apply_k(const float* __restrict__ in, const float* __restrict__ A,
                const float* __restrict__ B, const float* __restrict__ res,
                float* __restrict__ out, int total4){
  int i = blockIdx.x*256 + threadIdx.x; if(i >= total4) return;
  int cg = i & 31;
  f32x4 a = *(const f32x4*)(A + cg*4);
  f32x4 b = *(const f32x4*)(B + cg*4);
  f32x4 v = *(const f32x4*)(in + (size_t)i*4);
  f32x4 o;
  #pragma unroll
  for(int k=0;k<4;k++) o[k] = v[k]*a[k] + b[k];
  if(RES){
    f32x4 r = *(const f32x4*)(res + (size_t)i*4);
    #pragma unroll
    for(int k=0;k<4;k++) o[k] += r[k];
  }
  #pragma unroll
  for(int k=0;k<4;k++) o[k] = fmaxf(o[k], 0.f);
  *(f32x4*)(out + (size_t)i*4) = o;
}

// ---------------- edge MLP stage-1 stats: uint channel-pair loads -----------
__global__ __launch_bounds__(256)
void edge_stats1_k(const unsigned short* __restrict__ PQ, const int* __restrict__ esrc_csr,
                   const int* __restrict__ edst_csr, const float* __restrict__ b4,
                   float* __restrict__ s1, float* __restrict__ q1){
  int tid = threadIdx.x;
  int cp = tid & 127;          // channel pair: channels 2cp, 2cp+1
  int eh = tid >> 7;           // edge parity
  float bc0 = b4[2*cp], bc1 = b4[2*cp+1];
  float s0 = 0.f, q0 = 0.f, sv1 = 0.f, qv1 = 0.f;
  int j0 = blockIdx.x*256;
  #pragma unroll 4
  for(int j=0;j<128;j++){
    int p = j0 + 2*j + eh;
    int sr = esrc_csr[p], dn = edst_csr[p];
    unsigned int pu = *(const unsigned int*)(PQ + (size_t)sr*512 + 2*cp);
    unsigned int qu = *(const unsigned int*)(PQ + (size_t)dn*512 + 256 + 2*cp);
    float v0 = bf2f((unsigned short)(pu & 0xFFFFu)) + bf2f((unsigned short)(qu & 0xFFFFu)) + bc0;
    float v1 = bf2f((unsigned short)(pu >> 16))     + bf2f((unsigned short)(qu >> 16))     + bc1;
    s0 += v0; q0 += v0*v0; sv1 += v1; qv1 += v1*v1;
  }
  __shared__ float S0[256], Q0[256], S1[256], Q1[256];
  S0[tid] = s0; Q0[tid] = q0; S1[tid] = sv1; Q1[tid] = qv1;
  __syncthreads();
  if(tid < 128){
    atomicAdd(&s1[2*tid],   S0[tid]+S0[tid+128]);
    atomicAdd(&q1[2*tid],   Q0[tid]+Q0[tid+128]);
    atomicAdd(&s1[2*tid+1], S1[tid]+S1[tid+128]);
    atomicAdd(&q1[2*tid+1], Q1[tid]+Q1[tid+128]);
  }
}

// ---------------- edge GEMM1 v10: 2 tiles/block (tail-quantization fix) -----
// Same pipelined body as v9, T=4->2, grid 2500: with 2 blocks/CU resident
// (VGPR 252), grid 1250 ran as 512+512+226 -> ~23% tail waste; 2500 blocks
// -> ~2.4% waste, one prefetch-ahead tile of pipelining retained.
__device__ __forceinline__ unsigned short* at_addr(unsigned short* base, int row, int idx8){
  return base + row*256 + ((idx8 ^ (row & 7)) << 3);
}
template<bool STORE>
__global__ __launch_bounds__(256)
void edge_gemm1_k(const unsigned short* __restrict__ PQ, const int* __restrict__ esrc_csr,
                  const int* __restrict__ edst_csr, const float* __restrict__ SC1,
                  const float* __restrict__ SH1, const unsigned short* __restrict__ w6p,
                  const float* __restrict__ b6, unsigned short* __restrict__ t2,
                  float* __restrict__ s2, float* __restrict__ q2){
  __shared__ alignas(16) unsigned short At[64*256];   // 32 KB
  int tid = threadIdx.x;
  int lane = tid & 63, w = tid >> 6;
  int row = tid >> 2, chunk = tid & 3, c0 = chunk*64;
  int jb0 = blockIdx.x*128;
  const bf16x8* bp = (const bf16x8*)w6p;

  float statS[4] = {0.f,0.f,0.f,0.f};
  float statQ[4] = {0.f,0.f,0.f,0.f};
  float b6c[4];
  #pragma unroll
  for(int n=0;n<4;n++) b6c[n] = b6[(4*w+n)*16 + (lane & 15)];

  // warm tile 0's two P cachelines (chunks 0 and 4), keep row pointer
  const bf16x8* prowc;
  bf16x8 p0, p4;
  {
    int sr = esrc_csr[jb0 + row];
    prowc = (const bf16x8*)(PQ + (size_t)sr*512 + c0);
    p0 = prowc[0]; p4 = prowc[4];
  }

  for(int t=0; t<2; t++){
    int jb = jb0 + t*64;
    int dn = edst_csr[jb + row];
    const bf16x8* qrow = (const bf16x8*)(PQ + (size_t)dn*512 + 256 + c0);
    __syncthreads();   // previous tile's MFMA done reading At
    #pragma unroll
    for(int i=0;i<8;i++){
      bf16x8 pvi = (i==0) ? p0 : ((i==4) ? p4 : prowc[i]);
      bf16x8 qv = qrow[i];
      f32x4 sa = *(const f32x4*)(SC1 + c0 + i*8);
      f32x4 sb = *(const f32x4*)(SC1 + c0 + i*8 + 4);
      f32x4 ha = *(const f32x4*)(SH1 + c0 + i*8);
      f32x4 hb = *(const f32x4*)(SH1 + c0 + i*8 + 4);
      bf16x8 o;
      #pragma unroll
      for(int k=0;k<4;k++){
        float tv = bf2f((unsigned short)pvi[k]) + bf2f((unsigned short)qv[k]);
        o[k] = (short)f2bf(fmaxf(tv*sa[k] + ha[k], 0.f));
        float uv = bf2f((unsigned short)pvi[k+4]) + bf2f((unsigned short)qv[k+4]);
        o[k+4] = (short)f2bf(fmaxf(uv*sb[k] + hb[k], 0.f));
      }
      *(bf16x8*)at_addr(At, row, chunk*8 + i) = o;
    }
    // warm next tile's P lines now -> latency hides under MFMA+epilogue
    if(t < 1){
      int sr = esrc_csr[jb + 64 + row];
      prowc = (const bf16x8*)(PQ + (size_t)sr*512 + c0);
      p0 = prowc[0]; p4 = prowc[4];
    }
    __syncthreads();   // At ready
    f32x4 acc[4][4];
    #pragma unroll
    for(int i=0;i<4;i++)
      #pragma unroll
      for(int j=0;j<4;j++) acc[i][j] = (f32x4){0.f,0.f,0.f,0.f};
    #pragma unroll
    for(int ks=0; ks<8; ks++){
      bf16x8 bfr[4];
      #pragma unroll
      for(int n=0;n<4;n++) bfr[n] = bp[(size_t)((4*w+n)*8 + ks)*64 + lane];
      int idx8 = ks*4 + (lane >> 4);
      #pragma unroll
      for(int rt=0;rt<4;rt++){
        bf16x8 af = *(const bf16x8*)at_addr(At, rt*16 + (lane & 15), idx8);
        #pragma unroll
        for(int n=0;n<4;n++) acc[rt][n] = mfma_bf16(af, bfr[n], acc[rt][n]);
      }
    }
    // epilogue: bias, stats (reg-accumulated), t2 store
    #pragma unroll
    for(int n=0;n<4;n++){
      int col = (4*w+n)*16 + (lane & 15);
      #pragma unroll
      for(int rt=0;rt<4;rt++){
        f32x4 v = acc[rt][n];
        #pragma unroll
        for(int r=0;r<4;r++) v[r] += b6c[n];
        statS[n] += v[0]+v[1]+v[2]+v[3];
        statQ[n] += v[0]*v[0]+v[1]*v[1]+v[2]*v[2]+v[3]*v[3];
        if constexpr (STORE){
          #pragma unroll
          for(int r=0;r<4;r++){
            int orow = jb + rt*16 + ((lane >> 4) << 2) + r;
            t2[(size_t)orow*256 + col] = f2bf(v[r]);
          }
        }
      }
    }
  }
  // one stats reduce + atomic set per block
  #pragma unroll
  for(int n=0;n<4;n++){
    float ps = statS[n], pq = statQ[n];
    ps += __shfl_xor(ps, 16); ps += __shfl_xor(ps, 32);
    pq += __shfl_xor(pq, 16); pq += __shfl_xor(pq, 32);
    if(lane < 16){
      int col = (4*w+n)*16 + lane;
      atomicAdd(&s2[col], ps); atomicAdd(&q2[col], pq);
    }
  }
}

// ---------------- edge GEMM2: sequential t2 read, scatter out via eids ------
__global__ __launch_bounds__(256)
void edge_gemm2_k(const unsigned short* __restrict__ t2, const int* __restrict__ eids,
                  const float* __restrict__ SC2, const float* __restrict__ SH2,
                  const unsigned short* __restrict__ w8p, const float* __restrict__ b8,
                  float* __restrict__ outp){
  int lane = threadIdx.x & 63, w = threadIdx.x >> 6;
  int ebase = blockIdx.x*64 + w*16;
  const unsigned short* arow = t2 + (size_t)(ebase + (lane & 15))*256;
  int orig[4];
  #pragma unroll
  for(int r=0;r<4;r++) orig[r] = eids[ebase + ((lane >> 4) << 2) + r];
  f32x4 acc[6];
  #pragma unroll
  for(int i=0;i<6;i++) acc[i] = (f32x4){0.f,0.f,0.f,0.f};
  const bf16x8* bp = (const bf16x8*)w8p;
  #pragma unroll
  for(int ks=0; ks<8; ks++){
    int k0 = ks*32 + ((lane >> 4) << 3);
    bf16x8 tv = *(const bf16x8*)(arow + k0);
    f32x4 sc0 = *(const f32x4*)(SC2 + k0), sc1 = *(const f32x4*)(SC2 + k0 + 4);
    f32x4 sh0 = *(const f32x4*)(SH2 + k0), sh1 = *(const f32x4*)(SH2 + k0 + 4);
    bf16x8 af;
    #pragma unroll
    for(int i=0;i<4;i++){
      float t = fmaxf(bf2f((unsigned short)tv[i])*sc0[i]   + sh0[i], 0.f);
      af[i] = (short)f2bf(t);
      float u = fmaxf(bf2f((unsigned short)tv[i+4])*sc1[i] + sh1[i], 0.f);
      af[i+4] = (short)f2bf(u);
    }
    #pragma unroll
    for(int nt=0; nt<6; nt++)
      acc[nt] = mfma_bf16(af, bp[(size_t)(nt*8 + ks)*64 + lane], acc[nt]);
  }
  #pragma unroll
  for(int nt=0; nt<6; nt++){
    int col = nt*16 + (lane & 15);
    if(col < 86){
      float bb = b8[col];
      #pragma unroll
      for(int r=0;r<4;r++)
        outp[(size_t)orig[r]*86 + col] = acc[nt][r] + bb;
    }
  }
}

// ---------------- fallback: fused recompute (no t2 store), CSR order --------
__device__ __forceinline__ bf16x8 gather_t1_frag(const unsigned short* prow,
    const unsigned short* qrow, const float* SC1, const float* SH1, int k0){
  bf16x8 pv = *(const bf16x8*)(prow + k0);
  bf16x8 qv = *(const bf16x8*)(qrow + k0);
  f32x4 sc0 = *(const f32x4*)(SC1 + k0), sc1 = *(const f32x4*)(SC1 + k0 + 4);
  f32x4 sh0 = *(const f32x4*)(SH1 + k0), sh1 = *(const f32x4*)(SH1 + k0 + 4);
  bf16x8 af;
  #pragma unroll
  for(int i=0;i<4;i++){
    float t = bf2f((unsigned short)pv[i])   + bf2f((unsigned short)qv[i]);
    af[i] = (short)f2bf(fmaxf(t*sc0[i] + sh0[i], 0.f));
    float u = bf2f((unsigned short)pv[i+4]) + bf2f((unsigned short)qv[i+4]);
    af[i+4] = (short)f2bf(fmaxf(u*sc1[i] + sh1[i], 0.f));
  }
  return af;
}

__global__ __launch_bounds__(256)
void edge_fused_k(const unsigned short* __restrict__ PQ, const int* __restrict__ esrc_csr,
                  const int* __restrict__ edst_csr, const int* __restrict__ eids,
                  const float* __restrict__ SC1, const float* __restrict__ SH1,
                  const unsigned short* __restrict__ w6p, const float* __restrict__ b6,
                  const float* __restrict__ SC2, const float* __restrict__ SH2,
                  const unsigned short* __restrict__ w8p, const float* __restrict__ b8,
                  float* __restrict__ outp){
  int lane = threadIdx.x & 63, w = threadIdx.x >> 6;
  int jbase = blockIdx.x*64 + w*16;
  int jr = jbase + (lane & 15);
  int sr = esrc_csr[jr], dn = edst_csr[jr];
  int orig[4];
  #pragma unroll
  for(int r=0;r<4;r++) orig[r] = eids[jbase + ((lane >> 4) << 2) + r];
  const unsigned short* prow = PQ + (size_t)sr*512;
  const unsigned short* qrow = PQ + (size_t)dn*512 + 256;
  f32x4 acc[16];
  #pragma unroll
  for(int i=0;i<16;i++) acc[i] = (f32x4){0.f,0.f,0.f,0.f};
  const bf16x8* bp6 = (const bf16x8*)w6p;
  #pragma unroll
  for(int ks=0; ks<8; ks++){
    int k0 = ks*32 + ((lane >> 4) << 3);
    bf16x8 af = gather_t1_frag(prow, qrow, SC1, SH1, k0);
    #pragma unroll
    for(int nt=0; nt<16; nt++)
      acc[nt] = mfma_bf16(af, bp6[(size_t)(nt*8 + ks)*64 + lane], acc[nt]);
  }
  __shared__ alignas(16) unsigned short tile[4][16][264];
  #pragma unroll
  for(int nt=0; nt<16; nt++){
    int col = nt*16 + (lane & 15);
    float b6v = b6[col], sc = SC2[col], sh = SH2[col];
    #pragma unroll
    for(int r=0;r<4;r++){
      float t = fmaxf((acc[nt][r] + b6v)*sc + sh, 0.f);
      tile[w][((lane >> 4) << 2) + r][col] = f2bf(t);
    }
  }
  __syncthreads();
  f32x4 acc2[6];
  #pragma unroll
  for(int i=0;i<6;i++) acc2[i] = (f32x4){0.f,0.f,0.f,0.f};
  const bf16x8* bp8 = (const bf16x8*)w8p;
  #pragma unroll
  for(int ks=0; ks<8; ks++){
    int k0 = ks*32 + ((lane >> 4) << 3);
    bf16x8 af = *(const bf16x8*)&tile[w][lane & 15][k0];
    #pragma unroll
    for(int nt=0; nt<6; nt++)
      acc2[nt] = mfma_bf16(af, bp8[(size_t)(nt*8 + ks)*64 + lane], acc2[nt]);
  }
  #pragma unroll
  for(int nt=0; nt<6; nt++){
    int col = nt*16 + (lane & 15);
    if(col < 86){
      float bb = b8[col];
      #pragma unroll
      for(int r=0;r<4;r++)
        outp[(size_t)orig[r]*86 + col] = acc2[nt][r] + bb;
    }
  }
}

// =============================== host ========================================
extern "C" void kernel_launch(void* const* d_in, const int* in_sizes, int n_in,
                              void* d_out, int out_size, void* d_ws, size_t ws_size,
                              hipStream_t stream){
  const float* x      = (const float*)d_in[0];
  const int*   ei     = (const int*)  d_in[1];
  const float* w0     = (const float*)d_in[2];
  const float* b0     = (const float*)d_in[3];
  const float* att_s0 = (const float*)d_in[4];
  const float* att_d0 = (const float*)d_in[5];
  const float* w1     = (const float*)d_in[6];
  const float* b1     = (const float*)d_in[7];
  const float* w2     = (const float*)d_in[8];
  const float* b2     = (const float*)d_in[9];
  const float* att_s1 = (const float*)d_in[10];
  const float* att_d1 = (const float*)d_in[11];
  const float* w3     = (const float*)d_in[12];
  const float* b3     = (const float*)d_in[13];
  const float* w4     = (const float*)d_in[14];
  const float* b4     = (const float*)d_in[15];
  const float* w5     = (const float*)d_in[16];
  const float* b5     = (const float*)d_in[17];
  const float* w6     = (const float*)d_in[18];
  const float* b6     = (const float*)d_in[19];
  const float* w7     = (const float*)d_in[20];
  const float* b7     = (const float*)d_in[21];
  const float* w8     = (const float*)d_in[22];
  const float* b8     = (const float*)d_in[23];
  float* outp = (float*)d_out;
  char* ws = (char*)d_ws;
  const int* esrc = ei;
  const int* edst = ei + NE;

  size_t cur = 0;
  auto alloc = [&](size_t bytes){ size_t o = cur; cur = (cur + bytes + 255) & ~((size_t)255); return o; };
  size_t o_hbuf = alloc((size_t)20032*512*2);      // h1 -> h2 -> PQ (bf16)
  size_t o_out1 = alloc((size_t)NN*128*4);         // out1 -> out2
  size_t o_x1   = alloc((size_t)NN*128*4);
  size_t o_as   = alloc((size_t)NN*4*4);
  size_t o_ad   = alloc((size_t)NN*4*4);
  size_t o_ebuf = alloc((size_t)NE*4*4);
  size_t o_eids = alloc((size_t)NE*4);
  size_t o_escr = alloc((size_t)NE*4);
  size_t o_edcr = alloc((size_t)NE*4);
  size_t o_epos = alloc((size_t)NE*4);
  size_t o_w0p  = alloc((size_t)512*128*2);
  size_t o_w2p  = alloc((size_t)512*128*2);
  size_t o_w4p  = alloc((size_t)512*128*2);
  size_t o_w6p  = alloc((size_t)256*256*2);
  size_t o_w8p  = alloc((size_t)96*256*2);
  size_t o_rowp = alloc((size_t)(NN+1)*4);
  size_t o_nA1  = alloc(128*4); size_t o_nB1 = alloc(128*4);
  size_t o_nA2  = alloc(128*4); size_t o_nB2 = alloc(128*4);
  size_t o_SC1  = alloc(256*4); size_t o_SH1 = alloc(256*4);
  size_t o_SC2  = alloc(256*4); size_t o_SH2 = alloc(256*4);
  size_t zstart = cur;
  size_t o_cnt  = alloc((size_t)(NN+1)*4);
  size_t o_cnt2 = alloc((size_t)(NN+1)*4);
  size_t o_nS1  = alloc(128*4); size_t o_nQ1 = alloc(128*4);
  size_t o_nS2  = alloc(128*4); size_t o_nQ2 = alloc(128*4);
  size_t o_eS1  = alloc(256*4); size_t o_eQ1 = alloc(256*4);
  size_t o_eS2  = alloc(256*4); size_t o_eQ2 = alloc(256*4);
  size_t zbytes = cur - zstart;
  size_t o_t2 = cur;
  bool store_t2 = ws_size >= o_t2 + (size_t)NE*256*2;

  unsigned short* hbuf = (unsigned short*)(ws + o_hbuf);
  float* out1  = (float*)(ws + o_out1);
  float* x1b   = (float*)(ws + o_x1);
  float* asb   = (float*)(ws + o_as);
  float* adb   = (float*)(ws + o_ad);
  float* ebuf  = (float*)(ws + o_ebuf);
  int*   eids  = (int*)(ws + o_eids);
  int*   escr  = (int*)(ws + o_escr);
  int*   edcr  = (int*)(ws + o_edcr);
  int*   epos  = (int*)(ws + o_epos);
  unsigned short* w0p = (unsigned short*)(ws + o_w0p);
  unsigned short* w2p = (unsigned short*)(ws + o_w2p);
  unsigned short* w4p = (unsigned short*)(ws + o_w4p);
  unsigned short* w6p = (unsigned short*)(ws + o_w6p);
  unsigned short* w8p = (unsigned short*)(ws + o_w8p);
  int* rowp = (int*)(ws + o_rowp);
  int* cnt  = (int*)(ws + o_cnt);
  int* cnt2 = (int*)(ws + o_cnt2);
  float* nA1 = (float*)(ws+o_nA1); float* nB1 = (float*)(ws+o_nB1);
  float* nA2 = (float*)(ws+o_nA2); float* nB2 = (float*)(ws+o_nB2);
  float* SC1 = (float*)(ws+o_SC1); float* SH1 = (float*)(ws+o_SH1);
  float* SC2 = (float*)(ws+o_SC2); float* SH2 = (float*)(ws+o_SH2);
  float* nS1 = (float*)(ws+o_nS1); float* nQ1 = (float*)(ws+o_nQ1);
  float* nS2 = (float*)(ws+o_nS2); float* nQ2 = (float*)(ws+o_nQ2);
  float* eS1 = (float*)(ws+o_eS1); float* eQ1 = (float*)(ws+o_eQ1);
  float* eS2 = (float*)(ws+o_eS2); float* eQ2 = (float*)(ws+o_eQ2);
  unsigned short* t2p = (unsigned short*)(ws + o_t2);

  hipMemsetAsync(ws + zstart, 0, zbytes, stream);

  // weight packing
  pack_w_k<<<32*4, 64, 0, stream>>>(w0, w0p, 512, 128, 0);
  pack_w_k<<<32*4, 64, 0, stream>>>(w2, w2p, 512, 128, 0);
  pack_w_k<<<32*4, 64, 0, stream>>>(w4, w4p, 512, 128, 1);
  pack_w_k<<<16*8, 64, 0, stream>>>(w6, w6p, 256, 256, 0);
  pack_w_k<<<6*8,  64, 0, stream>>>(w8, w8p,  86, 256, 0);

  // CSR by dst (shared across both GAT layers + edge MLP)
  hist_k   <<<1250, 256, 0, stream>>>(edst, cnt);
  scan_k   <<<1, 1024, 0, stream>>>(cnt, rowp, NN);
  scatter_k<<<1250, 256, 0, stream>>>(esrc, edst, rowp, cnt2, eids, escr, edcr, epos);

  // ---- GAT layer 1 (alphas fused into GEMM epilogue) ----
  gemm_node_k<16,4,false,true><<<dim3(313,2), 256, 0, stream>>>(
      x, w0p, hbuf, nullptr, nullptr, nullptr, att_s0, att_d0, asb, adb, NN, 128, 512);
  edge_e_k<<<1250, 256, 0, stream>>>(asb, adb, esrc, edst, epos, ebuf);
  gat_aggregate_k<<<5000, 256, 0, stream>>>(hbuf, ebuf, rowp, escr, b0, out1, NN);
  bn_stats_k<<<256, 256, 0, stream>>>(out1, nS1, nQ1, NN);
  bn_finalize_k<<<1, 256, 0, stream>>>(nS1, nQ1, (float)NN, w1, b1, nullptr, nA1, nB1, 128);
  bn_apply_k<false><<<2500, 256, 0, stream>>>(out1, nA1, nB1, nullptr, x1b, NN*32);

  // ---- GAT layer 2 ----
  gemm_node_k<16,4,false,true><<<dim3(313,2), 256, 0, stream>>>(
      x1b, w2p, hbuf, nullptr, nullptr, nullptr, att_s1, att_d1, asb, adb, NN, 128, 512);
  edge_e_k<<<1250, 256, 0, stream>>>(asb, adb, esrc, edst, epos, ebuf);
  gat_aggregate_k<<<5000, 256, 0, stream>>>(hbuf, ebuf, rowp, escr, b2, out1, NN);
  bn_stats_k<<<256, 256, 0, stream>>>(out1, nS2, nQ2, NN);
  bn_finalize_k<<<1, 256, 0, stream>>>(nS2, nQ2, (float)NN, w3, b3, nullptr, nA2, nB2, 128);

  // ---- edge MLP ----
  // hfin = relu(bn2(out2) + x1) fused into the PQ GEMM's A-fragment build
  gemm_node_k<16,4,true,false><<<dim3(313,2), 256, 0, stream>>>(
      out1, w4p, hbuf, nA2, nB2, x1b, nullptr, nullptr, nullptr, nullptr, NN, 128, 512);
  edge_stats1_k<<<1250, 256, 0, stream>>>(hbuf, escr, edcr, b4, eS1, eQ1);
  bn_finalize_k<<<1, 256, 0, stream>>>(eS1, eQ1, (float)NE, w5, b5, b4, SC1, SH1, 256);
  if(store_t2){
    edge_gemm1_k<true><<<2500, 256, 0, stream>>>(hbuf, escr, edcr, SC1, SH1, w6p, b6, t2p, eS2, eQ2);
    bn_finalize_k<<<1, 256, 0, stream>>>(eS2, eQ2, (float)NE, w7, b7, nullptr, SC2, SH2, 256);
    edge_gemm2_k<<<5000, 256, 0, stream>>>(t2p, eids, SC2, SH2, w8p, b8, outp);
  } else {
    edge_gemm1_k<false><<<2500, 256, 0, stream>>>(hbuf, escr, edcr, SC1, SH1, w6p, b6, nullptr, eS2, eQ2);
    bn_finalize_k<<<1, 256, 0, stream>>>(eS2, eQ2, (float)NE, w7, b7, nullptr, SC2, SH2, 256);
    edge_fused_k<<<5000, 256, 0, stream>>>(hbuf, escr, edcr, eids, SC1, SH1, w6p, b6, SC2, SH2, w8p, b8, outp);
  }
}

// Round 11
// 666.481 us; speedup vs baseline: 1.1096x; 1.1096x over previous
//
#include <hip/hip_runtime.h>

#define NN 20000
#define NE 320000

using f32x4  = __attribute__((ext_vector_type(4))) float;
using bf16x8 = __attribute__((ext_vector_type(8))) short;

__device__ __forceinline__ float bf2f(unsigned short u){
  return __uint_as_float(((unsigned int)u) << 16);
}
__device__ __forceinline__ unsigned short f2bf(float f){
  unsigned int x = __float_as_uint(f);
  unsigned int r = ((x >> 16) & 1u) + 0x7FFFu;   // RNE
  return (unsigned short)((x + r) >> 16);
}
__device__ __forceinline__ f32x4 mfma_bf16(bf16x8 a, bf16x8 b, f32x4 c){
  return __builtin_amdgcn_mfma_f32_16x16x32_bf16(a, b, c, 0, 0, 0);
}

// ---------------- weight packing into MFMA B-fragment order ----------------
__global__ __launch_bounds__(64)
void pack_w_k(const float* __restrict__ W, unsigned short* __restrict__ out,
              int N, int K, int mode){
  int lane = threadIdx.x;
  int KS = K >> 5;
  int nt = blockIdx.x / KS, ks = blockIdx.x % KS;
  int row = nt*16 + (lane & 15);
  int kb  = ks*32 + ((lane >> 4) << 3);
  size_t ob = ((size_t)(nt*KS + ks)*64 + lane)*8;
  #pragma unroll
  for(int i=0;i<8;i++){
    int k = kb + i; float f = 0.f;
    if(row < N){
      f = (mode == 0) ? W[(size_t)row*K + k]
        : (row < 256 ? W[(size_t)row*256 + k] : W[(size_t)(row-256)*256 + 128 + k]);
    }
    out[ob + i] = f2bf(f);
  }
}

// ---------------- node GEMM: C_bf16[M,N] = A' @ W^T (packed) ---------------
template<int NT, int KS, bool FUSE, bool ALPHA>
__global__ __launch_bounds__(256)
void gemm_node_k(const float* __restrict__ A, const unsigned short* __restrict__ Bp,
                 unsigned short* __restrict__ C, const float* __restrict__ sc,
                 const float* __restrict__ sh, const float* __restrict__ res,
                 const float* __restrict__ att_s, const float* __restrict__ att_d,
                 float* __restrict__ as_, float* __restrict__ ad_,
                 int M, int K, int N){
  int lane = threadIdx.x & 63, w = threadIdx.x >> 6;
  int rowbase = blockIdx.x*64 + w*16;
  int nt0 = blockIdx.y * NT;
  f32x4 acc[NT];
  #pragma unroll
  for(int i=0;i<NT;i++) acc[i] = (f32x4){0.f,0.f,0.f,0.f};
  int arow = rowbase + (lane & 15); if(arow > M-1) arow = M-1;
  const float* ap = A + (size_t)arow*K + ((lane >> 4) << 3);
  const float* rp = FUSE ? (res + (size_t)arow*K + ((lane >> 4) << 3)) : nullptr;
  const bf16x8* bp = (const bf16x8*)Bp;
  #pragma unroll
  for(int ks=0; ks<KS; ks++){
    int k0 = ks*32 + ((lane >> 4) << 3);
    f32x4 a0 = *(const f32x4*)(ap + ks*32);
    f32x4 a1 = *(const f32x4*)(ap + ks*32 + 4);
    bf16x8 af;
    if constexpr (FUSE){
      f32x4 c0 = *(const f32x4*)(sc + k0), c1 = *(const f32x4*)(sc + k0 + 4);
      f32x4 h0 = *(const f32x4*)(sh + k0), h1 = *(const f32x4*)(sh + k0 + 4);
      f32x4 r0 = *(const f32x4*)(rp + ks*32), r1 = *(const f32x4*)(rp + ks*32 + 4);
      #pragma unroll
      for(int i=0;i<4;i++){
        af[i]   = (short)f2bf(fmaxf(a0[i]*c0[i] + h0[i] + r0[i], 0.f));
        af[i+4] = (short)f2bf(fmaxf(a1[i]*c1[i] + h1[i] + r1[i], 0.f));
      }
    } else {
      #pragma unroll
      for(int i=0;i<4;i++){ af[i] = (short)f2bf(a0[i]); af[i+4] = (short)f2bf(a1[i]); }
    }
    #pragma unroll
    for(int nt=0; nt<NT; nt++)
      acc[nt] = mfma_bf16(af, bp[((size_t)(nt0+nt)*KS + ks)*64 + lane], acc[nt]);
  }
  #pragma unroll
  for(int nt=0; nt<NT; nt++){
    int col = (nt0+nt)*16 + (lane & 15);
    #pragma unroll
    for(int r=0;r<4;r++){
      int row = rowbase + ((lane >> 4) << 2) + r;
      if(row < M) C[(size_t)row*N + col] = f2bf(acc[nt][r]);
    }
  }
  if constexpr (ALPHA){
    float ps[2][4] = {{0.f,0.f,0.f,0.f},{0.f,0.f,0.f,0.f}};
    float pd[2][4] = {{0.f,0.f,0.f,0.f},{0.f,0.f,0.f,0.f}};
    #pragma unroll
    for(int nt=0; nt<NT; nt++){
      int col = (nt0+nt)*16 + (lane & 15);
      float sv = att_s[col], dv = att_d[col];
      int hh = (col >> 7) & 1;
      #pragma unroll
      for(int r=0;r<4;r++){ ps[hh][r] += acc[nt][r]*sv; pd[hh][r] += acc[nt][r]*dv; }
    }
    #pragma unroll
    for(int m=1;m<16;m<<=1){
      #pragma unroll
      for(int hh=0;hh<2;hh++){
        #pragma unroll
        for(int r=0;r<4;r++){
          ps[hh][r] += __shfl_xor(ps[hh][r], m);
          pd[hh][r] += __shfl_xor(pd[hh][r], m);
        }
      }
    }
    if((lane & 15) == 0){
      int h0 = nt0 >> 3;
      #pragma unroll
      for(int r=0;r<4;r++){
        int row = rowbase + ((lane >> 4) << 2) + r;
        if(row < M){
          #pragma unroll
          for(int hh=0;hh<2;hh++){
            as_[row*4 + h0 + hh] = ps[hh][r];
            ad_[row*4 + h0 + hh] = pd[hh][r];
          }
        }
      }
    }
  }
}

// ---------------- per-edge leaky-relu logits, written in CSR order ----------
__global__ __launch_bounds__(256)
void edge_e_k(const float* __restrict__ as_, const float* __restrict__ ad_,
              const int* __restrict__ esrc, const int* __restrict__ edst,
              const int* __restrict__ epos, float* __restrict__ ebuf){
  int e = blockIdx.x*256 + threadIdx.x; if(e >= NE) return;
  f32x4 a = *(const f32x4*)(as_ + (size_t)esrc[e]*4);
  f32x4 b = *(const f32x4*)(ad_ + (size_t)edst[e]*4);
  f32x4 v;
  #pragma unroll
  for(int h=0;h<4;h++){ float t = a[h] + b[h]; v[h] = t > 0.f ? t : 0.2f*t; }
  *(f32x4*)(ebuf + (size_t)epos[e]*4) = v;
}

// ---------------- CSR build --------------------------------------------------
__global__ __launch_bounds__(256)
void hist_k(const int* __restrict__ edst, int* __restrict__ cnt){
  int e = blockIdx.x*256 + threadIdx.x; if(e >= NE) return;
  atomicAdd(&cnt[edst[e]], 1);
}
__global__ __launch_bounds__(1024)
void scan_k(const int* __restrict__ cnt, int* __restrict__ rowp, int n){
  __shared__ int part[1024];
  int t = threadIdx.x, base = t*20;
  int s = 0;
  for(int j=0;j<20;j++) if(base+j < n) s += cnt[base+j];
  part[t] = s;
  for(int off=1; off<1024; off<<=1){
    __syncthreads();
    int u = (t >= off) ? part[t-off] : 0;
    __syncthreads();
    part[t] += u;
  }
  __syncthreads();
  int run = part[t] - s;
  for(int j=0;j<20;j++){ int idx = base+j; if(idx < n){ rowp[idx] = run; run += cnt[idx]; } }
  if(t == 1023) rowp[n] = part[1023];
}
__global__ __launch_bounds__(256)
void scatter_k(const int* __restrict__ esrc, const int* __restrict__ edst,
               const int* __restrict__ rowp, int* __restrict__ cnt2,
               int* __restrict__ eids, int* __restrict__ esrc_csr,
               int* __restrict__ edst_csr, int* __restrict__ epos){
  int e = blockIdx.x*256 + threadIdx.x; if(e >= NE) return;
  int d = edst[e];
  int pos = atomicAdd(&cnt2[d], 1);
  int j = rowp[d] + pos;
  eids[j] = e;
  esrc_csr[j] = esrc[e];
  edst_csr[j] = d;
  epos[e] = j;
}

// ---------------- GAT aggregate: wave per node, CSR-ordered ebuf ------------
__global__ __launch_bounds__(256)
void gat_aggregate_k(const unsigned short* __restrict__ hbuf, const float* __restrict__ ebuf,
                     const int* __restrict__ rowp, const int* __restrict__ esrc_csr,
                     const float* __restrict__ bias, float* __restrict__ outn, int nN){
  int lane = threadIdx.x & 63, w = threadIdx.x >> 6;
  int node = blockIdx.x*4 + w; if(node >= nN) return;
  int start = rowp[node], end = rowp[node+1];
  int h = lane >> 4, jl = lane & 15;
  float m = -1e30f;
  for(int j = start + jl; j < end; j += 16) m = fmaxf(m, ebuf[(size_t)j*4 + h]);
  #pragma unroll
  for(int msk=1; msk<16; msk<<=1) m = fmaxf(m, __shfl_xor(m, msk));
  float s = 0.f;
  for(int j = start + jl; j < end; j += 16) s += expf(ebuf[(size_t)j*4 + h] - m);
  #pragma unroll
  for(int msk=1; msk<16; msk<<=1) s += __shfl_xor(s, msk);
  float inv = 1.f/(s + 1e-16f);
  float acc[8] = {0.f,0.f,0.f,0.f,0.f,0.f,0.f,0.f};
  int j = start;
  for(; j + 4 <= end; j += 4){
    int s0 = esrc_csr[j],   s1 = esrc_csr[j+1];
    int s2 = esrc_csr[j+2], s3 = esrc_csr[j+3];
    float e0 = ebuf[(size_t)j*4 + h],     e1 = ebuf[(size_t)(j+1)*4 + h];
    float e2 = ebuf[(size_t)(j+2)*4 + h], e3 = ebuf[(size_t)(j+3)*4 + h];
    bf16x8 v0 = *(const bf16x8*)(hbuf + (size_t)s0*512 + lane*8);
    bf16x8 v1 = *(const bf16x8*)(hbuf + (size_t)s1*512 + lane*8);
    bf16x8 v2 = *(const bf16x8*)(hbuf + (size_t)s2*512 + lane*8);
    bf16x8 v3 = *(const bf16x8*)(hbuf + (size_t)s3*512 + lane*8);
    float a0 = expf(e0 - m)*inv, a1 = expf(e1 - m)*inv;
    float a2 = expf(e2 - m)*inv, a3 = expf(e3 - m)*inv;
    #pragma unroll
    for(int i=0;i<8;i++)
      acc[i] += a0*bf2f((unsigned short)v0[i]) + a1*bf2f((unsigned short)v1[i])
              + a2*bf2f((unsigned short)v2[i]) + a3*bf2f((unsigned short)v3[i]);
  }
  for(; j < end; j++){
    int sa = esrc_csr[j];
    float aa = expf(ebuf[(size_t)j*4 + h] - m)*inv;
    bf16x8 va = *(const bf16x8*)(hbuf + (size_t)sa*512 + lane*8);
    #pragma unroll
    for(int i=0;i<8;i++) acc[i] += aa*bf2f((unsigned short)va[i]);
  }
  #pragma unroll
  for(int i=0;i<8;i++){ acc[i] += __shfl_xor(acc[i], 16); acc[i] += __shfl_xor(acc[i], 32); }
  if(lane < 16){
    #pragma unroll
    for(int i=0;i<8;i++)
      outn[(size_t)node*128 + lane*8 + i] = acc[i]*0.25f + bias[lane*8 + i];
  }
}

// ---------------- BN over nodes (128 ch), float4-vectorized -----------------
__global__ __launch_bounds__(256)
void bn_stats_k(const float* __restrict__ X, float* __restrict__ sum,
                float* __restrict__ sq, int M){
  int cg = threadIdx.x & 31, rg = threadIdx.x >> 5;   // 32 col-groups x 8 row-groups
  f32x4 s = {0.f,0.f,0.f,0.f}, q = {0.f,0.f,0.f,0.f};
  for(int r = blockIdx.x*8 + rg; r < M; r += 2048){
    f32x4 v = *(const f32x4*)(X + (size_t)r*128 + cg*4);
    s += v; q += v*v;
  }
  __shared__ f32x4 S[256], Q[256];
  S[threadIdx.x] = s; Q[threadIdx.x] = q; __syncthreads();
  if(rg == 0){
    f32x4 ts = {0.f,0.f,0.f,0.f}, tq = {0.f,0.f,0.f,0.f};
    #pragma unroll
    for(int g=0; g<8; g++){ ts += S[g*32+cg]; tq += Q[g*32+cg]; }
    #pragma unroll
    for(int k=0;k<4;k++){ atomicAdd(&sum[cg*4+k], ts[k]); atomicAdd(&sq[cg*4+k], tq[k]); }
  }
}

__global__ __launch_bounds__(256)
void bn_finalize_k(const float* __restrict__ sum, const float* __restrict__ sq, float count,
                   const float* __restrict__ wbn, const float* __restrict__ bbn,
                   const float* __restrict__ badd, float* __restrict__ A,
                   float* __restrict__ B, int C){
  int c = blockIdx.x*256 + threadIdx.x; if(c >= C) return;
  float mu = sum[c]/count;
  float var = sq[c]/count - mu*mu;
  float a = rsqrtf(var + 1e-5f) * wbn[c];
  float ba = badd ? badd[c] : 0.f;
  A[c] = a; B[c] = (ba - mu)*a + bbn[c];
}

template<bool RES>
__global__ __launch_bounds__(256)
void bn_apply_k(const float* __restrict__ in, const float* __restrict__ A,
                const float* __restrict__ B, const float* __restrict__ res,
                float* __restrict__ out, int total4){
  int i = blockIdx.x*256 + threadIdx.x; if(i >= total4) return;
  int cg = i & 31;
  f32x4 a = *(const f32x4*)(A + cg*4);
  f32x4 b = *(const f32x4*)(B + cg*4);
  f32x4 v = *(const f32x4*)(in + (size_t)i*4);
  f32x4 o;
  #pragma unroll
  for(int k=0;k<4;k++) o[k] = v[k]*a[k] + b[k];
  if(RES){
    f32x4 r = *(const f32x4*)(res + (size_t)i*4);
    #pragma unroll
    for(int k=0;k<4;k++) o[k] += r[k];
  }
  #pragma unroll
  for(int k=0;k<4;k++) o[k] = fmaxf(o[k], 0.f);
  *(f32x4*)(out + (size_t)i*4) = o;
}

// ---------------- edge MLP stage-1 stats (CSR order, scalar loads) ----------
__global__ __launch_bounds__(256)
void edge_stats1_k(const unsigned short* __restrict__ PQ, const int* __restrict__ esrc_csr,
                   const int* __restrict__ edst_csr, const float* __restrict__ b4,
                   float* __restrict__ s1, float* __restrict__ q1){
  int c = threadIdx.x;
  float bc = b4[c];
  float s = 0.f, q = 0.f;
  int j0 = blockIdx.x*256;
  #pragma unroll 8
  for(int j=0;j<256;j++){
    int p = j0 + j;
    int sr = esrc_csr[p], dn = edst_csr[p];
    float v = bf2f(PQ[(size_t)sr*512 + c]) + bf2f(PQ[(size_t)dn*512 + 256 + c]) + bc;
    s += v; q += v*v;
  }
  atomicAdd(&s1[c], s); atomicAdd(&q1[c], q);
}

// ---------------- edge GEMM1 v11 = v9 (best measured: 157us) ----------------
// 4 tiles/block, grid 1250, line-warm P prefetch, per-iter BN const loads,
// XOR-swizzled 32KB LDS, no min-waves bound (allocator picks ~252 VGPR).
__device__ __forceinline__ unsigned short* at_addr(unsigned short* base, int row, int idx8){
  return base + row*256 + ((idx8 ^ (row & 7)) << 3);
}
template<bool STORE>
__global__ __launch_bounds__(256)
void edge_gemm1_k(const unsigned short* __restrict__ PQ, const int* __restrict__ esrc_csr,
                  const int* __restrict__ edst_csr, const float* __restrict__ SC1,
                  const float* __restrict__ SH1, const unsigned short* __restrict__ w6p,
                  const float* __restrict__ b6, unsigned short* __restrict__ t2,
                  float* __restrict__ s2, float* __restrict__ q2){
  __shared__ alignas(16) unsigned short At[64*256];   // 32 KB
  int tid = threadIdx.x;
  int lane = tid & 63, w = tid >> 6;
  int row = tid >> 2, chunk = tid & 3, c0 = chunk*64;
  int jb0 = blockIdx.x*256;
  const bf16x8* bp = (const bf16x8*)w6p;

  float statS[4] = {0.f,0.f,0.f,0.f};
  float statQ[4] = {0.f,0.f,0.f,0.f};
  float b6c[4];
  #pragma unroll
  for(int n=0;n<4;n++) b6c[n] = b6[(4*w+n)*16 + (lane & 15)];

  // warm tile 0's two P cachelines (chunks 0 and 4), keep row pointer
  const bf16x8* prowc;
  bf16x8 p0, p4;
  {
    int sr = esrc_csr[jb0 + row];
    prowc = (const bf16x8*)(PQ + (size_t)sr*512 + c0);
    p0 = prowc[0]; p4 = prowc[4];
  }

  for(int t=0; t<4; t++){
    int jb = jb0 + t*64;
    int dn = edst_csr[jb + row];
    const bf16x8* qrow = (const bf16x8*)(PQ + (size_t)dn*512 + 256 + c0);
    __syncthreads();   // previous tile's MFMA done reading At
    #pragma unroll
    for(int i=0;i<8;i++){
      bf16x8 pvi = (i==0) ? p0 : ((i==4) ? p4 : prowc[i]);
      bf16x8 qv = qrow[i];
      f32x4 sa = *(const f32x4*)(SC1 + c0 + i*8);
      f32x4 sb = *(const f32x4*)(SC1 + c0 + i*8 + 4);
      f32x4 ha = *(const f32x4*)(SH1 + c0 + i*8);
      f32x4 hb = *(const f32x4*)(SH1 + c0 + i*8 + 4);
      bf16x8 o;
      #pragma unroll
      for(int k=0;k<4;k++){
        float tv = bf2f((unsigned short)pvi[k]) + bf2f((unsigned short)qv[k]);
        o[k] = (short)f2bf(fmaxf(tv*sa[k] + ha[k], 0.f));
        float uv = bf2f((unsigned short)pvi[k+4]) + bf2f((unsigned short)qv[k+4]);
        o[k+4] = (short)f2bf(fmaxf(uv*sb[k] + hb[k], 0.f));
      }
      *(bf16x8*)at_addr(At, row, chunk*8 + i) = o;
    }
    // warm next tile's P lines now -> latency hides under MFMA+epilogue
    if(t < 3){
      int sr = esrc_csr[jb + 64 + row];
      prowc = (const bf16x8*)(PQ + (size_t)sr*512 + c0);
      p0 = prowc[0]; p4 = prowc[4];
    }
    __syncthreads();   // At ready
    f32x4 acc[4][4];
    #pragma unroll
    for(int i=0;i<4;i++)
      #pragma unroll
      for(int j=0;j<4;j++) acc[i][j] = (f32x4){0.f,0.f,0.f,0.f};
    #pragma unroll
    for(int ks=0; ks<8; ks++){
      bf16x8 bfr[4];
      #pragma unroll
      for(int n=0;n<4;n++) bfr[n] = bp[(size_t)((4*w+n)*8 + ks)*64 + lane];
      int idx8 = ks*4 + (lane >> 4);
      #pragma unroll
      for(int rt=0;rt<4;rt++){
        bf16x8 af = *(const bf16x8*)at_addr(At, rt*16 + (lane & 15), idx8);
        #pragma unroll
        for(int n=0;n<4;n++) acc[rt][n] = mfma_bf16(af, bfr[n], acc[rt][n]);
      }
    }
    // epilogue: bias, stats (reg-accumulated), t2 store
    #pragma unroll
    for(int n=0;n<4;n++){
      int col = (4*w+n)*16 + (lane & 15);
      #pragma unroll
      for(int rt=0;rt<4;rt++){
        f32x4 v = acc[rt][n];
        #pragma unroll
        for(int r=0;r<4;r++) v[r] += b6c[n];
        statS[n] += v[0]+v[1]+v[2]+v[3];
        statQ[n] += v[0]*v[0]+v[1]*v[1]+v[2]*v[2]+v[3]*v[3];
        if constexpr (STORE){
          #pragma unroll
          for(int r=0;r<4;r++){
            int orow = jb + rt*16 + ((lane >> 4) << 2) + r;
            t2[(size_t)orow*256 + col] = f2bf(v[r]);
          }
        }
      }
    }
  }
  // one stats reduce + atomic set per block
  #pragma unroll
  for(int n=0;n<4;n++){
    float ps = statS[n], pq = statQ[n];
    ps += __shfl_xor(ps, 16); ps += __shfl_xor(ps, 32);
    pq += __shfl_xor(pq, 16); pq += __shfl_xor(pq, 32);
    if(lane < 16){
      int col = (4*w+n)*16 + lane;
      atomicAdd(&s2[col], ps); atomicAdd(&q2[col], pq);
    }
  }
}

// ---------------- edge GEMM2: sequential t2 read, scatter out via eids ------
__global__ __launch_bounds__(256)
void edge_gemm2_k(const unsigned short* __restrict__ t2, const int* __restrict__ eids,
                  const float* __restrict__ SC2, const float* __restrict__ SH2,
                  const unsigned short* __restrict__ w8p, const float* __restrict__ b8,
                  float* __restrict__ outp){
  int lane = threadIdx.x & 63, w = threadIdx.x >> 6;
  int ebase = blockIdx.x*64 + w*16;
  const unsigned short* arow = t2 + (size_t)(ebase + (lane & 15))*256;
  int orig[4];
  #pragma unroll
  for(int r=0;r<4;r++) orig[r] = eids[ebase + ((lane >> 4) << 2) + r];
  f32x4 acc[6];
  #pragma unroll
  for(int i=0;i<6;i++) acc[i] = (f32x4){0.f,0.f,0.f,0.f};
  const bf16x8* bp = (const bf16x8*)w8p;
  #pragma unroll
  for(int ks=0; ks<8; ks++){
    int k0 = ks*32 + ((lane >> 4) << 3);
    bf16x8 tv = *(const bf16x8*)(arow + k0);
    f32x4 sc0 = *(const f32x4*)(SC2 + k0), sc1 = *(const f32x4*)(SC2 + k0 + 4);
    f32x4 sh0 = *(const f32x4*)(SH2 + k0), sh1 = *(const f32x4*)(SH2 + k0 + 4);
    bf16x8 af;
    #pragma unroll
    for(int i=0;i<4;i++){
      float t = fmaxf(bf2f((unsigned short)tv[i])*sc0[i]   + sh0[i], 0.f);
      af[i] = (short)f2bf(t);
      float u = fmaxf(bf2f((unsigned short)tv[i+4])*sc1[i] + sh1[i], 0.f);
      af[i+4] = (short)f2bf(u);
    }
    #pragma unroll
    for(int nt=0; nt<6; nt++)
      acc[nt] = mfma_bf16(af, bp[(size_t)(nt*8 + ks)*64 + lane], acc[nt]);
  }
  #pragma unroll
  for(int nt=0; nt<6; nt++){
    int col = nt*16 + (lane & 15);
    if(col < 86){
      float bb = b8[col];
      #pragma unroll
      for(int r=0;r<4;r++)
        outp[(size_t)orig[r]*86 + col] = acc[nt][r] + bb;
    }
  }
}

// ---------------- fallback: fused recompute (no t2 store), CSR order --------
__device__ __forceinline__ bf16x8 gather_t1_frag(const unsigned short* prow,
    const unsigned short* qrow, const float* SC1, const float* SH1, int k0){
  bf16x8 pv = *(const bf16x8*)(prow + k0);
  bf16x8 qv = *(const bf16x8*)(qrow + k0);
  f32x4 sc0 = *(const f32x4*)(SC1 + k0), sc1 = *(const f32x4*)(SC1 + k0 + 4);
  f32x4 sh0 = *(const f32x4*)(SH1 + k0), sh1 = *(const f32x4*)(SH1 + k0 + 4);
  bf16x8 af;
  #pragma unroll
  for(int i=0;i<4;i++){
    float t = bf2f((unsigned short)pv[i])   + bf2f((unsigned short)qv[i]);
    af[i] = (short)f2bf(fmaxf(t*sc0[i] + sh0[i], 0.f));
    float u = bf2f((unsigned short)pv[i+4]) + bf2f((unsigned short)qv[i+4]);
    af[i+4] = (short)f2bf(fmaxf(u*sc1[i] + sh1[i], 0.f));
  }
  return af;
}

__global__ __launch_bounds__(256)
void edge_fused_k(const unsigned short* __restrict__ PQ, const int* __restrict__ esrc_csr,
                  const int* __restrict__ edst_csr, const int* __restrict__ eids,
                  const float* __restrict__ SC1, const float* __restrict__ SH1,
                  const unsigned short* __restrict__ w6p, const float* __restrict__ b6,
                  const float* __restrict__ SC2, const float* __restrict__ SH2,
                  const unsigned short* __restrict__ w8p, const float* __restrict__ b8,
                  float* __restrict__ outp){
  int lane = threadIdx.x & 63, w = threadIdx.x >> 6;
  int jbase = blockIdx.x*64 + w*16;
  int jr = jbase + (lane & 15);
  int sr = esrc_csr[jr], dn = edst_csr[jr];
  int orig[4];
  #pragma unroll
  for(int r=0;r<4;r++) orig[r] = eids[jbase + ((lane >> 4) << 2) + r];
  const unsigned short* prow = PQ + (size_t)sr*512;
  const unsigned short* qrow = PQ + (size_t)dn*512 + 256;
  f32x4 acc[16];
  #pragma unroll
  for(int i=0;i<16;i++) acc[i] = (f32x4){0.f,0.f,0.f,0.f};
  const bf16x8* bp6 = (const bf16x8*)w6p;
  #pragma unroll
  for(int ks=0; ks<8; ks++){
    int k0 = ks*32 + ((lane >> 4) << 3);
    bf16x8 af = gather_t1_frag(prow, qrow, SC1, SH1, k0);
    #pragma unroll
    for(int nt=0; nt<16; nt++)
      acc[nt] = mfma_bf16(af, bp6[(size_t)(nt*8 + ks)*64 + lane], acc[nt]);
  }
  __shared__ alignas(16) unsigned short tile[4][16][264];
  #pragma unroll
  for(int nt=0; nt<16; nt++){
    int col = nt*16 + (lane & 15);
    float b6v = b6[col], sc = SC2[col], sh = SH2[col];
    #pragma unroll
    for(int r=0;r<4;r++){
      float t = fmaxf((acc[nt][r] + b6v)*sc + sh, 0.f);
      tile[w][((lane >> 4) << 2) + r][col] = f2bf(t);
    }
  }
  __syncthreads();
  f32x4 acc2[6];
  #pragma unroll
  for(int i=0;i<6;i++) acc2[i] = (f32x4){0.f,0.f,0.f,0.f};
  const bf16x8* bp8 = (const bf16x8*)w8p;
  #pragma unroll
  for(int ks=0; ks<8; ks++){
    int k0 = ks*32 + ((lane >> 4) << 3);
    bf16x8 af = *(const bf16x8*)&tile[w][lane & 15][k0];
    #pragma unroll
    for(int nt=0; nt<6; nt++)
      acc2[nt] = mfma_bf16(af, bp8[(size_t)(nt*8 + ks)*64 + lane], acc2[nt]);
  }
  #pragma unroll
  for(int nt=0; nt<6; nt++){
    int col = nt*16 + (lane & 15);
    if(col < 86){
      float bb = b8[col];
      #pragma unroll
      for(int r=0;r<4;r++)
        outp[(size_t)orig[r]*86 + col] = acc2[nt][r] + bb;
    }
  }
}

// =============================== host ========================================
extern "C" void kernel_launch(void* const* d_in, const int* in_sizes, int n_in,
                              void* d_out, int out_size, void* d_ws, size_t ws_size,
                              hipStream_t stream){
  const float* x      = (const float*)d_in[0];
  const int*   ei     = (const int*)  d_in[1];
  const float* w0     = (const float*)d_in[2];
  const float* b0     = (const float*)d_in[3];
  const float* att_s0 = (const float*)d_in[4];
  const float* att_d0 = (const float*)d_in[5];
  const float* w1     = (const float*)d_in[6];
  const float* b1     = (const float*)d_in[7];
  const float* w2     = (const float*)d_in[8];
  const float* b2     = (const float*)d_in[9];
  const float* att_s1 = (const float*)d_in[10];
  const float* att_d1 = (const float*)d_in[11];
  const float* w3     = (const float*)d_in[12];
  const float* b3     = (const float*)d_in[13];
  const float* w4     = (const float*)d_in[14];
  const float* b4     = (const float*)d_in[15];
  const float* w5     = (const float*)d_in[16];
  const float* b5     = (const float*)d_in[17];
  const float* w6     = (const float*)d_in[18];
  const float* b6     = (const float*)d_in[19];
  const float* w7     = (const float*)d_in[20];
  const float* b7     = (const float*)d_in[21];
  const float* w8     = (const float*)d_in[22];
  const float* b8     = (const float*)d_in[23];
  float* outp = (float*)d_out;
  char* ws = (char*)d_ws;
  const int* esrc = ei;
  const int* edst = ei + NE;

  size_t cur = 0;
  auto alloc = [&](size_t bytes){ size_t o = cur; cur = (cur + bytes + 255) & ~((size_t)255); return o; };
  size_t o_hbuf = alloc((size_t)20032*512*2);      // h1 -> h2 -> PQ (bf16)
  size_t o_out1 = alloc((size_t)NN*128*4);         // out1 -> out2
  size_t o_x1   = alloc((size_t)NN*128*4);
  size_t o_as   = alloc((size_t)NN*4*4);
  size_t o_ad   = alloc((size_t)NN*4*4);
  size_t o_ebuf = alloc((size_t)NE*4*4);
  size_t o_eids = alloc((size_t)NE*4);
  size_t o_escr = alloc((size_t)NE*4);
  size_t o_edcr = alloc((size_t)NE*4);
  size_t o_epos = alloc((size_t)NE*4);
  size_t o_w0p  = alloc((size_t)512*128*2);
  size_t o_w2p  = alloc((size_t)512*128*2);
  size_t o_w4p  = alloc((size_t)512*128*2);
  size_t o_w6p  = alloc((size_t)256*256*2);
  size_t o_w8p  = alloc((size_t)96*256*2);
  size_t o_rowp = alloc((size_t)(NN+1)*4);
  size_t o_nA1  = alloc(128*4); size_t o_nB1 = alloc(128*4);
  size_t o_nA2  = alloc(128*4); size_t o_nB2 = alloc(128*4);
  size_t o_SC1  = alloc(256*4); size_t o_SH1 = alloc(256*4);
  size_t o_SC2  = alloc(256*4); size_t o_SH2 = alloc(256*4);
  size_t zstart = cur;
  size_t o_cnt  = alloc((size_t)(NN+1)*4);
  size_t o_cnt2 = alloc((size_t)(NN+1)*4);
  size_t o_nS1  = alloc(128*4); size_t o_nQ1 = alloc(128*4);
  size_t o_nS2  = alloc(128*4); size_t o_nQ2 = alloc(128*4);
  size_t o_eS1  = alloc(256*4); size_t o_eQ1 = alloc(256*4);
  size_t o_eS2  = alloc(256*4); size_t o_eQ2 = alloc(256*4);
  size_t zbytes = cur - zstart;
  size_t o_t2 = cur;
  bool store_t2 = ws_size >= o_t2 + (size_t)NE*256*2;

  unsigned short* hbuf = (unsigned short*)(ws + o_hbuf);
  float* out1  = (float*)(ws + o_out1);
  float* x1b   = (float*)(ws + o_x1);
  float* asb   = (float*)(ws + o_as);
  float* adb   = (float*)(ws + o_ad);
  float* ebuf  = (float*)(ws + o_ebuf);
  int*   eids  = (int*)(ws + o_eids);
  int*   escr  = (int*)(ws + o_escr);
  int*   edcr  = (int*)(ws + o_edcr);
  int*   epos  = (int*)(ws + o_epos);
  unsigned short* w0p = (unsigned short*)(ws + o_w0p);
  unsigned short* w2p = (unsigned short*)(ws + o_w2p);
  unsigned short* w4p = (unsigned short*)(ws + o_w4p);
  unsigned short* w6p = (unsigned short*)(ws + o_w6p);
  unsigned short* w8p = (unsigned short*)(ws + o_w8p);
  int* rowp = (int*)(ws + o_rowp);
  int* cnt  = (int*)(ws + o_cnt);
  int* cnt2 = (int*)(ws + o_cnt2);
  float* nA1 = (float*)(ws+o_nA1); float* nB1 = (float*)(ws+o_nB1);
  float* nA2 = (float*)(ws+o_nA2); float* nB2 = (float*)(ws+o_nB2);
  float* SC1 = (float*)(ws+o_SC1); float* SH1 = (float*)(ws+o_SH1);
  float* SC2 = (float*)(ws+o_SC2); float* SH2 = (float*)(ws+o_SH2);
  float* nS1 = (float*)(ws+o_nS1); float* nQ1 = (float*)(ws+o_nQ1);
  float* nS2 = (float*)(ws+o_nS2); float* nQ2 = (float*)(ws+o_nQ2);
  float* eS1 = (float*)(ws+o_eS1); float* eQ1 = (float*)(ws+o_eQ1);
  float* eS2 = (float*)(ws+o_eS2); float* eQ2 = (float*)(ws+o_eQ2);
  unsigned short* t2p = (unsigned short*)(ws + o_t2);

  hipMemsetAsync(ws + zstart, 0, zbytes, stream);

  // weight packing
  pack_w_k<<<32*4, 64, 0, stream>>>(w0, w0p, 512, 128, 0);
  pack_w_k<<<32*4, 64, 0, stream>>>(w2, w2p, 512, 128, 0);
  pack_w_k<<<32*4, 64, 0, stream>>>(w4, w4p, 512, 128, 1);
  pack_w_k<<<16*8, 64, 0, stream>>>(w6, w6p, 256, 256, 0);
  pack_w_k<<<6*8,  64, 0, stream>>>(w8, w8p,  86, 256, 0);

  // CSR by dst (shared across both GAT layers + edge MLP)
  hist_k   <<<1250, 256, 0, stream>>>(edst, cnt);
  scan_k   <<<1, 1024, 0, stream>>>(cnt, rowp, NN);
  scatter_k<<<1250, 256, 0, stream>>>(esrc, edst, rowp, cnt2, eids, escr, edcr, epos);

  // ---- GAT layer 1 (alphas fused into GEMM epilogue) ----
  gemm_node_k<16,4,false,true><<<dim3(313,2), 256, 0, stream>>>(
      x, w0p, hbuf, nullptr, nullptr, nullptr, att_s0, att_d0, asb, adb, NN, 128, 512);
  edge_e_k<<<1250, 256, 0, stream>>>(asb, adb, esrc, edst, epos, ebuf);
  gat_aggregate_k<<<5000, 256, 0, stream>>>(hbuf, ebuf, rowp, escr, b0, out1, NN);
  bn_stats_k<<<256, 256, 0, stream>>>(out1, nS1, nQ1, NN);
  bn_finalize_k<<<1, 256, 0, stream>>>(nS1, nQ1, (float)NN, w1, b1, nullptr, nA1, nB1, 128);
  bn_apply_k<false><<<2500, 256, 0, stream>>>(out1, nA1, nB1, nullptr, x1b, NN*32);

  // ---- GAT layer 2 ----
  gemm_node_k<16,4,false,true><<<dim3(313,2), 256, 0, stream>>>(
      x1b, w2p, hbuf, nullptr, nullptr, nullptr, att_s1, att_d1, asb, adb, NN, 128, 512);
  edge_e_k<<<1250, 256, 0, stream>>>(asb, adb, esrc, edst, epos, ebuf);
  gat_aggregate_k<<<5000, 256, 0, stream>>>(hbuf, ebuf, rowp, escr, b2, out1, NN);
  bn_stats_k<<<256, 256, 0, stream>>>(out1, nS2, nQ2, NN);
  bn_finalize_k<<<1, 256, 0, stream>>>(nS2, nQ2, (float)NN, w3, b3, nullptr, nA2, nB2, 128);

  // ---- edge MLP ----
  // hfin = relu(bn2(out2) + x1) fused into the PQ GEMM's A-fragment build
  gemm_node_k<16,4,true,false><<<dim3(313,2), 256, 0, stream>>>(
      out1, w4p, hbuf, nA2, nB2, x1b, nullptr, nullptr, nullptr, nullptr, NN, 128, 512);
  edge_stats1_k<<<1250, 256, 0, stream>>>(hbuf, escr, edcr, b4, eS1, eQ1);
  bn_finalize_k<<<1, 256, 0, stream>>>(eS1, eQ1, (float)NE, w5, b5, b4, SC1, SH1, 256);
  if(store_t2){
    edge_gemm1_k<true><<<1250, 256, 0, stream>>>(hbuf, escr, edcr, SC1, SH1, w6p, b6, t2p, eS2, eQ2);
    bn_finalize_k<<<1, 256, 0, stream>>>(eS2, eQ2, (float)NE, w7, b7, nullptr, SC2, SH2, 256);
    edge_gemm2_k<<<5000, 256, 0, stream>>>(t2p, eids, SC2, SH2, w8p, b8, outp);
  } else {
    edge_gemm1_k<false><<<1250, 256, 0, stream>>>(hbuf, escr, edcr, SC1, SH1, w6p, b6, nullptr, eS2, eQ2);
    bn_finalize_k<<<1, 256, 0, stream>>>(eS2, eQ2, (float)NE, w7, b7, nullptr, SC2, SH2, 256);
    edge_fused_k<<<5000, 256, 0, stream>>>(hbuf, escr, edcr, eids, SC1, SH1, w6p, b6, SC2, SH2, w8p, b8, outp);
  }
}

// Round 12
// 649.279 us; speedup vs baseline: 1.1390x; 1.0265x over previous
//
#include <hip/hip_runtime.h>

#define NN 20000
#define NE 320000

using f32x4  = __attribute__((ext_vector_type(4))) float;
using bf16x8 = __attribute__((ext_vector_type(8))) short;

__device__ __forceinline__ float bf2f(unsigned short u){
  return __uint_as_float(((unsigned int)u) << 16);
}
__device__ __forceinline__ unsigned short f2bf(float f){
  unsigned int x = __float_as_uint(f);
  unsigned int r = ((x >> 16) & 1u) + 0x7FFFu;   // RNE
  return (unsigned short)((x + r) >> 16);
}
__device__ __forceinline__ f32x4 mfma_bf16(bf16x8 a, bf16x8 b, f32x4 c){
  return __builtin_amdgcn_mfma_f32_16x16x32_bf16(a, b, c, 0, 0, 0);
}

// ---------------- weight packing into MFMA B-fragment order ----------------
__global__ __launch_bounds__(64)
void pack_w_k(const float* __restrict__ W, unsigned short* __restrict__ out,
              int N, int K, int mode){
  int lane = threadIdx.x;
  int KS = K >> 5;
  int nt = blockIdx.x / KS, ks = blockIdx.x % KS;
  int row = nt*16 + (lane & 15);
  int kb  = ks*32 + ((lane >> 4) << 3);
  size_t ob = ((size_t)(nt*KS + ks)*64 + lane)*8;
  #pragma unroll
  for(int i=0;i<8;i++){
    int k = kb + i; float f = 0.f;
    if(row < N){
      f = (mode == 0) ? W[(size_t)row*K + k]
        : (row < 256 ? W[(size_t)row*256 + k] : W[(size_t)(row-256)*256 + 128 + k]);
    }
    out[ob + i] = f2bf(f);
  }
}

// ---------------- node GEMM: C_bf16[M,N] = A' @ W^T (packed) ---------------
template<int NT, int KS, bool FUSE, bool ALPHA>
__global__ __launch_bounds__(256)
void gemm_node_k(const float* __restrict__ A, const unsigned short* __restrict__ Bp,
                 unsigned short* __restrict__ C, const float* __restrict__ sc,
                 const float* __restrict__ sh, const float* __restrict__ res,
                 const float* __restrict__ att_s, const float* __restrict__ att_d,
                 float* __restrict__ as_, float* __restrict__ ad_,
                 int M, int K, int N){
  int lane = threadIdx.x & 63, w = threadIdx.x >> 6;
  int rowbase = blockIdx.x*64 + w*16;
  int nt0 = blockIdx.y * NT;
  f32x4 acc[NT];
  #pragma unroll
  for(int i=0;i<NT;i++) acc[i] = (f32x4){0.f,0.f,0.f,0.f};
  int arow = rowbase + (lane & 15); if(arow > M-1) arow = M-1;
  const float* ap = A + (size_t)arow*K + ((lane >> 4) << 3);
  const float* rp = FUSE ? (res + (size_t)arow*K + ((lane >> 4) << 3)) : nullptr;
  const bf16x8* bp = (const bf16x8*)Bp;
  #pragma unroll
  for(int ks=0; ks<KS; ks++){
    int k0 = ks*32 + ((lane >> 4) << 3);
    f32x4 a0 = *(const f32x4*)(ap + ks*32);
    f32x4 a1 = *(const f32x4*)(ap + ks*32 + 4);
    bf16x8 af;
    if constexpr (FUSE){
      f32x4 c0 = *(const f32x4*)(sc + k0), c1 = *(const f32x4*)(sc + k0 + 4);
      f32x4 h0 = *(const f32x4*)(sh + k0), h1 = *(const f32x4*)(sh + k0 + 4);
      f32x4 r0 = *(const f32x4*)(rp + ks*32), r1 = *(const f32x4*)(rp + ks*32 + 4);
      #pragma unroll
      for(int i=0;i<4;i++){
        af[i]   = (short)f2bf(fmaxf(a0[i]*c0[i] + h0[i] + r0[i], 0.f));
        af[i+4] = (short)f2bf(fmaxf(a1[i]*c1[i] + h1[i] + r1[i], 0.f));
      }
    } else {
      #pragma unroll
      for(int i=0;i<4;i++){ af[i] = (short)f2bf(a0[i]); af[i+4] = (short)f2bf(a1[i]); }
    }
    #pragma unroll
    for(int nt=0; nt<NT; nt++)
      acc[nt] = mfma_bf16(af, bp[((size_t)(nt0+nt)*KS + ks)*64 + lane], acc[nt]);
  }
  #pragma unroll
  for(int nt=0; nt<NT; nt++){
    int col = (nt0+nt)*16 + (lane & 15);
    #pragma unroll
    for(int r=0;r<4;r++){
      int row = rowbase + ((lane >> 4) << 2) + r;
      if(row < M) C[(size_t)row*N + col] = f2bf(acc[nt][r]);
    }
  }
  if constexpr (ALPHA){
    float ps[2][4] = {{0.f,0.f,0.f,0.f},{0.f,0.f,0.f,0.f}};
    float pd[2][4] = {{0.f,0.f,0.f,0.f},{0.f,0.f,0.f,0.f}};
    #pragma unroll
    for(int nt=0; nt<NT; nt++){
      int col = (nt0+nt)*16 + (lane & 15);
      float sv = att_s[col], dv = att_d[col];
      int hh = (col >> 7) & 1;
      #pragma unroll
      for(int r=0;r<4;r++){ ps[hh][r] += acc[nt][r]*sv; pd[hh][r] += acc[nt][r]*dv; }
    }
    #pragma unroll
    for(int m=1;m<16;m<<=1){
      #pragma unroll
      for(int hh=0;hh<2;hh++){
        #pragma unroll
        for(int r=0;r<4;r++){
          ps[hh][r] += __shfl_xor(ps[hh][r], m);
          pd[hh][r] += __shfl_xor(pd[hh][r], m);
        }
      }
    }
    if((lane & 15) == 0){
      int h0 = nt0 >> 3;
      #pragma unroll
      for(int r=0;r<4;r++){
        int row = rowbase + ((lane >> 4) << 2) + r;
        if(row < M){
          #pragma unroll
          for(int hh=0;hh<2;hh++){
            as_[row*4 + h0 + hh] = ps[hh][r];
            ad_[row*4 + h0 + hh] = pd[hh][r];
          }
        }
      }
    }
  }
}

// ---------------- per-edge leaky-relu logits, written in CSR order ----------
__global__ __launch_bounds__(256)
void edge_e_k(const float* __restrict__ as_, const float* __restrict__ ad_,
              const int* __restrict__ esrc, const int* __restrict__ edst,
              const int* __restrict__ epos, float* __restrict__ ebuf){
  int e = blockIdx.x*256 + threadIdx.x; if(e >= NE) return;
  f32x4 a = *(const f32x4*)(as_ + (size_t)esrc[e]*4);
  f32x4 b = *(const f32x4*)(ad_ + (size_t)edst[e]*4);
  f32x4 v;
  #pragma unroll
  for(int h=0;h<4;h++){ float t = a[h] + b[h]; v[h] = t > 0.f ? t : 0.2f*t; }
  *(f32x4*)(ebuf + (size_t)epos[e]*4) = v;
}

// ---------------- CSR build --------------------------------------------------
__global__ __launch_bounds__(256)
void hist_k(const int* __restrict__ edst, int* __restrict__ cnt){
  int e = blockIdx.x*256 + threadIdx.x; if(e >= NE) return;
  atomicAdd(&cnt[edst[e]], 1);
}
__global__ __launch_bounds__(1024)
void scan_k(const int* __restrict__ cnt, int* __restrict__ rowp, int n){
  __shared__ int part[1024];
  int t = threadIdx.x, base = t*20;
  int s = 0;
  for(int j=0;j<20;j++) if(base+j < n) s += cnt[base+j];
  part[t] = s;
  for(int off=1; off<1024; off<<=1){
    __syncthreads();
    int u = (t >= off) ? part[t-off] : 0;
    __syncthreads();
    part[t] += u;
  }
  __syncthreads();
  int run = part[t] - s;
  for(int j=0;j<20;j++){ int idx = base+j; if(idx < n){ rowp[idx] = run; run += cnt[idx]; } }
  if(t == 1023) rowp[n] = part[1023];
}
__global__ __launch_bounds__(256)
void scatter_k(const int* __restrict__ esrc, const int* __restrict__ edst,
               const int* __restrict__ rowp, int* __restrict__ cnt2,
               int* __restrict__ eids, int* __restrict__ esrc_csr,
               int* __restrict__ edst_csr, int* __restrict__ epos){
  int e = blockIdx.x*256 + threadIdx.x; if(e >= NE) return;
  int d = edst[e];
  int pos = atomicAdd(&cnt2[d], 1);
  int j = rowp[d] + pos;
  eids[j] = e;
  esrc_csr[j] = esrc[e];
  edst_csr[j] = d;
  epos[e] = j;
}

// ---------------- GAT aggregate: wave per node, CSR-ordered ebuf ------------
__global__ __launch_bounds__(256)
void gat_aggregate_k(const unsigned short* __restrict__ hbuf, const float* __restrict__ ebuf,
                     const int* __restrict__ rowp, const int* __restrict__ esrc_csr,
                     const float* __restrict__ bias, float* __restrict__ outn, int nN){
  int lane = threadIdx.x & 63, w = threadIdx.x >> 6;
  int node = blockIdx.x*4 + w; if(node >= nN) return;
  int start = rowp[node], end = rowp[node+1];
  int h = lane >> 4, jl = lane & 15;
  float m = -1e30f;
  for(int j = start + jl; j < end; j += 16) m = fmaxf(m, ebuf[(size_t)j*4 + h]);
  #pragma unroll
  for(int msk=1; msk<16; msk<<=1) m = fmaxf(m, __shfl_xor(m, msk));
  float s = 0.f;
  for(int j = start + jl; j < end; j += 16) s += expf(ebuf[(size_t)j*4 + h] - m);
  #pragma unroll
  for(int msk=1; msk<16; msk<<=1) s += __shfl_xor(s, msk);
  float inv = 1.f/(s + 1e-16f);
  float acc[8] = {0.f,0.f,0.f,0.f,0.f,0.f,0.f,0.f};
  int j = start;
  for(; j + 4 <= end; j += 4){
    int s0 = esrc_csr[j],   s1 = esrc_csr[j+1];
    int s2 = esrc_csr[j+2], s3 = esrc_csr[j+3];
    float e0 = ebuf[(size_t)j*4 + h],     e1 = ebuf[(size_t)(j+1)*4 + h];
    float e2 = ebuf[(size_t)(j+2)*4 + h], e3 = ebuf[(size_t)(j+3)*4 + h];
    bf16x8 v0 = *(const bf16x8*)(hbuf + (size_t)s0*512 + lane*8);
    bf16x8 v1 = *(const bf16x8*)(hbuf + (size_t)s1*512 + lane*8);
    bf16x8 v2 = *(const bf16x8*)(hbuf + (size_t)s2*512 + lane*8);
    bf16x8 v3 = *(const bf16x8*)(hbuf + (size_t)s3*512 + lane*8);
    float a0 = expf(e0 - m)*inv, a1 = expf(e1 - m)*inv;
    float a2 = expf(e2 - m)*inv, a3 = expf(e3 - m)*inv;
    #pragma unroll
    for(int i=0;i<8;i++)
      acc[i] += a0*bf2f((unsigned short)v0[i]) + a1*bf2f((unsigned short)v1[i])
              + a2*bf2f((unsigned short)v2[i]) + a3*bf2f((unsigned short)v3[i]);
  }
  for(; j < end; j++){
    int sa = esrc_csr[j];
    float aa = expf(ebuf[(size_t)j*4 + h] - m)*inv;
    bf16x8 va = *(const bf16x8*)(hbuf + (size_t)sa*512 + lane*8);
    #pragma unroll
    for(int i=0;i<8;i++) acc[i] += aa*bf2f((unsigned short)va[i]);
  }
  #pragma unroll
  for(int i=0;i<8;i++){ acc[i] += __shfl_xor(acc[i], 16); acc[i] += __shfl_xor(acc[i], 32); }
  if(lane < 16){
    #pragma unroll
    for(int i=0;i<8;i++)
      outn[(size_t)node*128 + lane*8 + i] = acc[i]*0.25f + bias[lane*8 + i];
  }
}

// ---------------- BN over nodes (128 ch), float4-vectorized -----------------
__global__ __launch_bounds__(256)
void bn_stats_k(const float* __restrict__ X, float* __restrict__ sum,
                float* __restrict__ sq, int M){
  int cg = threadIdx.x & 31, rg = threadIdx.x >> 5;   // 32 col-groups x 8 row-groups
  f32x4 s = {0.f,0.f,0.f,0.f}, q = {0.f,0.f,0.f,0.f};
  for(int r = blockIdx.x*8 + rg; r < M; r += 2048){
    f32x4 v = *(const f32x4*)(X + (size_t)r*128 + cg*4);
    s += v; q += v*v;
  }
  __shared__ f32x4 S[256], Q[256];
  S[threadIdx.x] = s; Q[threadIdx.x] = q; __syncthreads();
  if(rg == 0){
    f32x4 ts = {0.f,0.f,0.f,0.f}, tq = {0.f,0.f,0.f,0.f};
    #pragma unroll
    for(int g=0; g<8; g++){ ts += S[g*32+cg]; tq += Q[g*32+cg]; }
    #pragma unroll
    for(int k=0;k<4;k++){ atomicAdd(&sum[cg*4+k], ts[k]); atomicAdd(&sq[cg*4+k], tq[k]); }
  }
}

__global__ __launch_bounds__(256)
void bn_finalize_k(const float* __restrict__ sum, const float* __restrict__ sq, float count,
                   const float* __restrict__ wbn, const float* __restrict__ bbn,
                   const float* __restrict__ badd, float* __restrict__ A,
                   float* __restrict__ B, int C){
  int c = blockIdx.x*256 + threadIdx.x; if(c >= C) return;
  float mu = sum[c]/count;
  float var = sq[c]/count - mu*mu;
  float a = rsqrtf(var + 1e-5f) * wbn[c];
  float ba = badd ? badd[c] : 0.f;
  A[c] = a; B[c] = (ba - mu)*a + bbn[c];
}

template<bool RES>
__global__ __launch_bounds__(256)
void bn_apply_k(const float* __restrict__ in, const float* __restrict__ A,
                const float* __restrict__ B, const float* __restrict__ res,
                float* __restrict__ out, int total4){
  int i = blockIdx.x*256 + threadIdx.x; if(i >= total4) return;
  int cg = i & 31;
  f32x4 a = *(const f32x4*)(A + cg*4);
  f32x4 b = *(const f32x4*)(B + cg*4);
  f32x4 v = *(const f32x4*)(in + (size_t)i*4);
  f32x4 o;
  #pragma unroll
  for(int k=0;k<4;k++) o[k] = v[k]*a[k] + b[k];
  if(RES){
    f32x4 r = *(const f32x4*)(res + (size_t)i*4);
    #pragma unroll
    for(int k=0;k<4;k++) o[k] += r[k];
  }
  #pragma unroll
  for(int k=0;k<4;k++) o[k] = fmaxf(o[k], 0.f);
  *(f32x4*)(out + (size_t)i*4) = o;
}

// ---------------- edge MLP stage-1 stats (CSR order, scalar loads) ----------
__global__ __launch_bounds__(256)
void edge_stats1_k(const unsigned short* __restrict__ PQ, const int* __restrict__ esrc_csr,
                   const int* __restrict__ edst_csr, const float* __restrict__ b4,
                   float* __restrict__ s1, float* __restrict__ q1){
  int c = threadIdx.x;
  float bc = b4[c];
  float s = 0.f, q = 0.f;
  int j0 = blockIdx.x*256;
  #pragma unroll 8
  for(int j=0;j<256;j++){
    int p = j0 + j;
    int sr = esrc_csr[p], dn = edst_csr[p];
    float v = bf2f(PQ[(size_t)sr*512 + c]) + bf2f(PQ[(size_t)dn*512 + 256 + c]) + bc;
    s += v; q += v*v;
  }
  atomicAdd(&s1[c], s); atomicAdd(&q1[c], q);
}

// ---------------- prescale PQ in place: P'=P*SC1, Q'=Q*SC1+SH1 --------------
// After this, stage-1 BN+relu is just relu(P'[src]+Q'[dst]) -> no BN consts
// live in edge_gemm1 (frees ~128 hoisted VGPRs there).
__global__ __launch_bounds__(256)
void prescale_k(unsigned short* __restrict__ PQ, const float* __restrict__ SC1,
                const float* __restrict__ SH1, int total8){
  int i = blockIdx.x*256 + threadIdx.x; if(i >= total8) return;
  int cg = i & 63;                 // group of 8 cols within the 512-wide row
  bf16x8 v = *(bf16x8*)(PQ + (size_t)i*8);
  bf16x8 o;
  if(cg < 32){                     // P half: cols cg*8..+7
    f32x4 s0 = *(const f32x4*)(SC1 + cg*8);
    f32x4 s1 = *(const f32x4*)(SC1 + cg*8 + 4);
    #pragma unroll
    for(int k=0;k<4;k++){
      o[k]   = (short)f2bf(bf2f((unsigned short)v[k])*s0[k]);
      o[k+4] = (short)f2bf(bf2f((unsigned short)v[k+4])*s1[k]);
    }
  } else {                         // Q half: cols (cg-32)*8..+7
    int c = (cg-32)*8;
    f32x4 s0 = *(const f32x4*)(SC1 + c);
    f32x4 s1 = *(const f32x4*)(SC1 + c + 4);
    f32x4 h0 = *(const f32x4*)(SH1 + c);
    f32x4 h1 = *(const f32x4*)(SH1 + c + 4);
    #pragma unroll
    for(int k=0;k<4;k++){
      o[k]   = (short)f2bf(bf2f((unsigned short)v[k])*s0[k]   + h0[k]);
      o[k+4] = (short)f2bf(bf2f((unsigned short)v[k+4])*s1[k] + h1[k]);
    }
  }
  *(bf16x8*)(PQ + (size_t)i*8) = o;
}

// ---------------- edge GEMM1 v12: v9 structure, prescaled PQ ---------------
// Stage is now relu(P'+Q') only -> far fewer live regs in the unrolled loop.
__device__ __forceinline__ unsigned short* at_addr(unsigned short* base, int row, int idx8){
  return base + row*256 + ((idx8 ^ (row & 7)) << 3);
}
template<bool STORE>
__global__ __launch_bounds__(256)
void edge_gemm1_k(const unsigned short* __restrict__ PQ, const int* __restrict__ esrc_csr,
                  const int* __restrict__ edst_csr, const unsigned short* __restrict__ w6p,
                  const float* __restrict__ b6, unsigned short* __restrict__ t2,
                  float* __restrict__ s2, float* __restrict__ q2){
  __shared__ alignas(16) unsigned short At[64*256];   // 32 KB
  int tid = threadIdx.x;
  int lane = tid & 63, w = tid >> 6;
  int row = tid >> 2, chunk = tid & 3, c0 = chunk*64;
  int jb0 = blockIdx.x*256;
  const bf16x8* bp = (const bf16x8*)w6p;

  float statS[4] = {0.f,0.f,0.f,0.f};
  float statQ[4] = {0.f,0.f,0.f,0.f};
  float b6c[4];
  #pragma unroll
  for(int n=0;n<4;n++) b6c[n] = b6[(4*w+n)*16 + (lane & 15)];

  // warm tile 0's two P cachelines (chunks 0 and 4), keep row pointer
  const bf16x8* prowc;
  bf16x8 p0, p4;
  {
    int sr = esrc_csr[jb0 + row];
    prowc = (const bf16x8*)(PQ + (size_t)sr*512 + c0);
    p0 = prowc[0]; p4 = prowc[4];
  }

  for(int t=0; t<4; t++){
    int jb = jb0 + t*64;
    int dn = edst_csr[jb + row];
    const bf16x8* qrow = (const bf16x8*)(PQ + (size_t)dn*512 + 256 + c0);
    __syncthreads();   // previous tile's MFMA done reading At
    #pragma unroll
    for(int i=0;i<8;i++){
      bf16x8 pvi = (i==0) ? p0 : ((i==4) ? p4 : prowc[i]);
      bf16x8 qv = qrow[i];
      bf16x8 o;
      #pragma unroll
      for(int k=0;k<8;k++){
        float tv = bf2f((unsigned short)pvi[k]) + bf2f((unsigned short)qv[k]);
        o[k] = (short)f2bf(fmaxf(tv, 0.f));
      }
      *(bf16x8*)at_addr(At, row, chunk*8 + i) = o;
    }
    // warm next tile's P lines now -> latency hides under MFMA+epilogue
    if(t < 3){
      int sr = esrc_csr[jb + 64 + row];
      prowc = (const bf16x8*)(PQ + (size_t)sr*512 + c0);
      p0 = prowc[0]; p4 = prowc[4];
    }
    __syncthreads();   // At ready
    f32x4 acc[4][4];
    #pragma unroll
    for(int i=0;i<4;i++)
      #pragma unroll
      for(int j=0;j<4;j++) acc[i][j] = (f32x4){0.f,0.f,0.f,0.f};
    #pragma unroll
    for(int ks=0; ks<8; ks++){
      bf16x8 bfr[4];
      #pragma unroll
      for(int n=0;n<4;n++) bfr[n] = bp[(size_t)((4*w+n)*8 + ks)*64 + lane];
      int idx8 = ks*4 + (lane >> 4);
      #pragma unroll
      for(int rt=0;rt<4;rt++){
        bf16x8 af = *(const bf16x8*)at_addr(At, rt*16 + (lane & 15), idx8);
        #pragma unroll
        for(int n=0;n<4;n++) acc[rt][n] = mfma_bf16(af, bfr[n], acc[rt][n]);
      }
    }
    // epilogue: bias, stats (reg-accumulated), t2 store
    #pragma unroll
    for(int n=0;n<4;n++){
      int col = (4*w+n)*16 + (lane & 15);
      #pragma unroll
      for(int rt=0;rt<4;rt++){
        f32x4 v = acc[rt][n];
        #pragma unroll
        for(int r=0;r<4;r++) v[r] += b6c[n];
        statS[n] += v[0]+v[1]+v[2]+v[3];
        statQ[n] += v[0]*v[0]+v[1]*v[1]+v[2]*v[2]+v[3]*v[3];
        if constexpr (STORE){
          #pragma unroll
          for(int r=0;r<4;r++){
            int orow = jb + rt*16 + ((lane >> 4) << 2) + r;
            t2[(size_t)orow*256 + col] = f2bf(v[r]);
          }
        }
      }
    }
  }
  // one stats reduce + atomic set per block
  #pragma unroll
  for(int n=0;n<4;n++){
    float ps = statS[n], pq = statQ[n];
    ps += __shfl_xor(ps, 16); ps += __shfl_xor(ps, 32);
    pq += __shfl_xor(pq, 16); pq += __shfl_xor(pq, 32);
    if(lane < 16){
      int col = (4*w+n)*16 + lane;
      atomicAdd(&s2[col], ps); atomicAdd(&q2[col], pq);
    }
  }
}

// ---------------- edge GEMM2: sequential t2 read, scatter out via eids ------
__global__ __launch_bounds__(256)
void edge_gemm2_k(const unsigned short* __restrict__ t2, const int* __restrict__ eids,
                  const float* __restrict__ SC2, const float* __restrict__ SH2,
                  const unsigned short* __restrict__ w8p, const float* __restrict__ b8,
                  float* __restrict__ outp){
  int lane = threadIdx.x & 63, w = threadIdx.x >> 6;
  int ebase = blockIdx.x*64 + w*16;
  const unsigned short* arow = t2 + (size_t)(ebase + (lane & 15))*256;
  int orig[4];
  #pragma unroll
  for(int r=0;r<4;r++) orig[r] = eids[ebase + ((lane >> 4) << 2) + r];
  f32x4 acc[6];
  #pragma unroll
  for(int i=0;i<6;i++) acc[i] = (f32x4){0.f,0.f,0.f,0.f};
  const bf16x8* bp = (const bf16x8*)w8p;
  #pragma unroll
  for(int ks=0; ks<8; ks++){
    int k0 = ks*32 + ((lane >> 4) << 3);
    bf16x8 tv = *(const bf16x8*)(arow + k0);
    f32x4 sc0 = *(const f32x4*)(SC2 + k0), sc1 = *(const f32x4*)(SC2 + k0 + 4);
    f32x4 sh0 = *(const f32x4*)(SH2 + k0), sh1 = *(const f32x4*)(SH2 + k0 + 4);
    bf16x8 af;
    #pragma unroll
    for(int i=0;i<4;i++){
      float t = fmaxf(bf2f((unsigned short)tv[i])*sc0[i]   + sh0[i], 0.f);
      af[i] = (short)f2bf(t);
      float u = fmaxf(bf2f((unsigned short)tv[i+4])*sc1[i] + sh1[i], 0.f);
      af[i+4] = (short)f2bf(u);
    }
    #pragma unroll
    for(int nt=0; nt<6; nt++)
      acc[nt] = mfma_bf16(af, bp[(size_t)(nt*8 + ks)*64 + lane], acc[nt]);
  }
  #pragma unroll
  for(int nt=0; nt<6; nt++){
    int col = nt*16 + (lane & 15);
    if(col < 86){
      float bb = b8[col];
      #pragma unroll
      for(int r=0;r<4;r++)
        outp[(size_t)orig[r]*86 + col] = acc[nt][r] + bb;
    }
  }
}

// ---------------- fallback: fused recompute (no t2 store), prescaled PQ -----
__device__ __forceinline__ bf16x8 gather_t1_frag(const unsigned short* prow,
    const unsigned short* qrow, int k0){
  bf16x8 pv = *(const bf16x8*)(prow + k0);
  bf16x8 qv = *(const bf16x8*)(qrow + k0);
  bf16x8 af;
  #pragma unroll
  for(int i=0;i<8;i++){
    float t = bf2f((unsigned short)pv[i]) + bf2f((unsigned short)qv[i]);
    af[i] = (short)f2bf(fmaxf(t, 0.f));
  }
  return af;
}

__global__ __launch_bounds__(256)
void edge_fused_k(const unsigned short* __restrict__ PQ, const int* __restrict__ esrc_csr,
                  const int* __restrict__ edst_csr, const int* __restrict__ eids,
                  const unsigned short* __restrict__ w6p, const float* __restrict__ b6,
                  const float* __restrict__ SC2, const float* __restrict__ SH2,
                  const unsigned short* __restrict__ w8p, const float* __restrict__ b8,
                  float* __restrict__ outp){
  int lane = threadIdx.x & 63, w = threadIdx.x >> 6;
  int jbase = blockIdx.x*64 + w*16;
  int jr = jbase + (lane & 15);
  int sr = esrc_csr[jr], dn = edst_csr[jr];
  int orig[4];
  #pragma unroll
  for(int r=0;r<4;r++) orig[r] = eids[jbase + ((lane >> 4) << 2) + r];
  const unsigned short* prow = PQ + (size_t)sr*512;
  const unsigned short* qrow = PQ + (size_t)dn*512 + 256;
  f32x4 acc[16];
  #pragma unroll
  for(int i=0;i<16;i++) acc[i] = (f32x4){0.f,0.f,0.f,0.f};
  const bf16x8* bp6 = (const bf16x8*)w6p;
  #pragma unroll
  for(int ks=0; ks<8; ks++){
    int k0 = ks*32 + ((lane >> 4) << 3);
    bf16x8 af = gather_t1_frag(prow, qrow, k0);
    #pragma unroll
    for(int nt=0; nt<16; nt++)
      acc[nt] = mfma_bf16(af, bp6[(size_t)(nt*8 + ks)*64 + lane], acc[nt]);
  }
  __shared__ alignas(16) unsigned short tile[4][16][264];
  #pragma unroll
  for(int nt=0; nt<16; nt++){
    int col = nt*16 + (lane & 15);
    float b6v = b6[col], sc = SC2[col], sh = SH2[col];
    #pragma unroll
    for(int r=0;r<4;r++){
      float t = fmaxf((acc[nt][r] + b6v)*sc + sh, 0.f);
      tile[w][((lane >> 4) << 2) + r][col] = f2bf(t);
    }
  }
  __syncthreads();
  f32x4 acc2[6];
  #pragma unroll
  for(int i=0;i<6;i++) acc2[i] = (f32x4){0.f,0.f,0.f,0.f};
  const bf16x8* bp8 = (const bf16x8*)w8p;
  #pragma unroll
  for(int ks=0; ks<8; ks++){
    int k0 = ks*32 + ((lane >> 4) << 3);
    bf16x8 af = *(const bf16x8*)&tile[w][lane & 15][k0];
    #pragma unroll
    for(int nt=0; nt<6; nt++)
      acc2[nt] = mfma_bf16(af, bp8[(size_t)(nt*8 + ks)*64 + lane], acc2[nt]);
  }
  #pragma unroll
  for(int nt=0; nt<6; nt++){
    int col = nt*16 + (lane & 15);
    if(col < 86){
      float bb = b8[col];
      #pragma unroll
      for(int r=0;r<4;r++)
        outp[(size_t)orig[r]*86 + col] = acc2[nt][r] + bb;
    }
  }
}

// =============================== host ========================================
extern "C" void kernel_launch(void* const* d_in, const int* in_sizes, int n_in,
                              void* d_out, int out_size, void* d_ws, size_t ws_size,
                              hipStream_t stream){
  const float* x      = (const float*)d_in[0];
  const int*   ei     = (const int*)  d_in[1];
  const float* w0     = (const float*)d_in[2];
  const float* b0     = (const float*)d_in[3];
  const float* att_s0 = (const float*)d_in[4];
  const float* att_d0 = (const float*)d_in[5];
  const float* w1     = (const float*)d_in[6];
  const float* b1     = (const float*)d_in[7];
  const float* w2     = (const float*)d_in[8];
  const float* b2     = (const float*)d_in[9];
  const float* att_s1 = (const float*)d_in[10];
  const float* att_d1 = (const float*)d_in[11];
  const float* w3     = (const float*)d_in[12];
  const float* b3     = (const float*)d_in[13];
  const float* w4     = (const float*)d_in[14];
  const float* b4     = (const float*)d_in[15];
  const float* w5     = (const float*)d_in[16];
  const float* b5     = (const float*)d_in[17];
  const float* w6     = (const float*)d_in[18];
  const float* b6     = (const float*)d_in[19];
  const float* w7     = (const float*)d_in[20];
  const float* b7     = (const float*)d_in[21];
  const float* w8     = (const float*)d_in[22];
  const float* b8     = (const float*)d_in[23];
  float* outp = (float*)d_out;
  char* ws = (char*)d_ws;
  const int* esrc = ei;
  const int* edst = ei + NE;

  size_t cur = 0;
  auto alloc = [&](size_t bytes){ size_t o = cur; cur = (cur + bytes + 255) & ~((size_t)255); return o; };
  size_t o_hbuf = alloc((size_t)20032*512*2);      // h1 -> h2 -> PQ (bf16)
  size_t o_out1 = alloc((size_t)NN*128*4);         // out1 -> out2
  size_t o_x1   = alloc((size_t)NN*128*4);
  size_t o_as   = alloc((size_t)NN*4*4);
  size_t o_ad   = alloc((size_t)NN*4*4);
  size_t o_ebuf = alloc((size_t)NE*4*4);
  size_t o_eids = alloc((size_t)NE*4);
  size_t o_escr = alloc((size_t)NE*4);
  size_t o_edcr = alloc((size_t)NE*4);
  size_t o_epos = alloc((size_t)NE*4);
  size_t o_w0p  = alloc((size_t)512*128*2);
  size_t o_w2p  = alloc((size_t)512*128*2);
  size_t o_w4p  = alloc((size_t)512*128*2);
  size_t o_w6p  = alloc((size_t)256*256*2);
  size_t o_w8p  = alloc((size_t)96*256*2);
  size_t o_rowp = alloc((size_t)(NN+1)*4);
  size_t o_nA1  = alloc(128*4); size_t o_nB1 = alloc(128*4);
  size_t o_nA2  = alloc(128*4); size_t o_nB2 = alloc(128*4);
  size_t o_SC1  = alloc(256*4); size_t o_SH1 = alloc(256*4);
  size_t o_SC2  = alloc(256*4); size_t o_SH2 = alloc(256*4);
  size_t zstart = cur;
  size_t o_cnt  = alloc((size_t)(NN+1)*4);
  size_t o_cnt2 = alloc((size_t)(NN+1)*4);
  size_t o_nS1  = alloc(128*4); size_t o_nQ1 = alloc(128*4);
  size_t o_nS2  = alloc(128*4); size_t o_nQ2 = alloc(128*4);
  size_t o_eS1  = alloc(256*4); size_t o_eQ1 = alloc(256*4);
  size_t o_eS2  = alloc(256*4); size_t o_eQ2 = alloc(256*4);
  size_t zbytes = cur - zstart;
  size_t o_t2 = cur;
  bool store_t2 = ws_size >= o_t2 + (size_t)NE*256*2;

  unsigned short* hbuf = (unsigned short*)(ws + o_hbuf);
  float* out1  = (float*)(ws + o_out1);
  float* x1b   = (float*)(ws + o_x1);
  float* asb   = (float*)(ws + o_as);
  float* adb   = (float*)(ws + o_ad);
  float* ebuf  = (float*)(ws + o_ebuf);
  int*   eids  = (int*)(ws + o_eids);
  int*   escr  = (int*)(ws + o_escr);
  int*   edcr  = (int*)(ws + o_edcr);
  int*   epos  = (int*)(ws + o_epos);
  unsigned short* w0p = (unsigned short*)(ws + o_w0p);
  unsigned short* w2p = (unsigned short*)(ws + o_w2p);
  unsigned short* w4p = (unsigned short*)(ws + o_w4p);
  unsigned short* w6p = (unsigned short*)(ws + o_w6p);
  unsigned short* w8p = (unsigned short*)(ws + o_w8p);
  int* rowp = (int*)(ws + o_rowp);
  int* cnt  = (int*)(ws + o_cnt);
  int* cnt2 = (int*)(ws + o_cnt2);
  float* nA1 = (float*)(ws+o_nA1); float* nB1 = (float*)(ws+o_nB1);
  float* nA2 = (float*)(ws+o_nA2); float* nB2 = (float*)(ws+o_nB2);
  float* SC1 = (float*)(ws+o_SC1); float* SH1 = (float*)(ws+o_SH1);
  float* SC2 = (float*)(ws+o_SC2); float* SH2 = (float*)(ws+o_SH2);
  float* nS1 = (float*)(ws+o_nS1); float* nQ1 = (float*)(ws+o_nQ1);
  float* nS2 = (float*)(ws+o_nS2); float* nQ2 = (float*)(ws+o_nQ2);
  float* eS1 = (float*)(ws+o_eS1); float* eQ1 = (float*)(ws+o_eQ1);
  float* eS2 = (float*)(ws+o_eS2); float* eQ2 = (float*)(ws+o_eQ2);
  unsigned short* t2p = (unsigned short*)(ws + o_t2);

  hipMemsetAsync(ws + zstart, 0, zbytes, stream);

  // weight packing
  pack_w_k<<<32*4, 64, 0, stream>>>(w0, w0p, 512, 128, 0);
  pack_w_k<<<32*4, 64, 0, stream>>>(w2, w2p, 512, 128, 0);
  pack_w_k<<<32*4, 64, 0, stream>>>(w4, w4p, 512, 128, 1);
  pack_w_k<<<16*8, 64, 0, stream>>>(w6, w6p, 256, 256, 0);
  pack_w_k<<<6*8,  64, 0, stream>>>(w8, w8p,  86, 256, 0);

  // CSR by dst (shared across both GAT layers + edge MLP)
  hist_k   <<<1250, 256, 0, stream>>>(edst, cnt);
  scan_k   <<<1, 1024, 0, stream>>>(cnt, rowp, NN);
  scatter_k<<<1250, 256, 0, stream>>>(esrc, edst, rowp, cnt2, eids, escr, edcr, epos);

  // ---- GAT layer 1 (alphas fused into GEMM epilogue) ----
  gemm_node_k<16,4,false,true><<<dim3(313,2), 256, 0, stream>>>(
      x, w0p, hbuf, nullptr, nullptr, nullptr, att_s0, att_d0, asb, adb, NN, 128, 512);
  edge_e_k<<<1250, 256, 0, stream>>>(asb, adb, esrc, edst, epos, ebuf);
  gat_aggregate_k<<<5000, 256, 0, stream>>>(hbuf, ebuf, rowp, escr, b0, out1, NN);
  bn_stats_k<<<256, 256, 0, stream>>>(out1, nS1, nQ1, NN);
  bn_finalize_k<<<1, 256, 0, stream>>>(nS1, nQ1, (float)NN, w1, b1, nullptr, nA1, nB1, 128);
  bn_apply_k<false><<<2500, 256, 0, stream>>>(out1, nA1, nB1, nullptr, x1b, NN*32);

  // ---- GAT layer 2 ----
  gemm_node_k<16,4,false,true><<<dim3(313,2), 256, 0, stream>>>(
      x1b, w2p, hbuf, nullptr, nullptr, nullptr, att_s1, att_d1, asb, adb, NN, 128, 512);
  edge_e_k<<<1250, 256, 0, stream>>>(asb, adb, esrc, edst, epos, ebuf);
  gat_aggregate_k<<<5000, 256, 0, stream>>>(hbuf, ebuf, rowp, escr, b2, out1, NN);
  bn_stats_k<<<256, 256, 0, stream>>>(out1, nS2, nQ2, NN);
  bn_finalize_k<<<1, 256, 0, stream>>>(nS2, nQ2, (float)NN, w3, b3, nullptr, nA2, nB2, 128);

  // ---- edge MLP ----
  // hfin = relu(bn2(out2) + x1) fused into the PQ GEMM's A-fragment build
  gemm_node_k<16,4,true,false><<<dim3(313,2), 256, 0, stream>>>(
      out1, w4p, hbuf, nA2, nB2, x1b, nullptr, nullptr, nullptr, nullptr, NN, 128, 512);
  edge_stats1_k<<<1250, 256, 0, stream>>>(hbuf, escr, edcr, b4, eS1, eQ1);
  bn_finalize_k<<<1, 256, 0, stream>>>(eS1, eQ1, (float)NE, w5, b5, b4, SC1, SH1, 256);
  // fold BN1 into PQ in place: P'=P*SC1, Q'=Q*SC1+SH1
  prescale_k<<<5000, 256, 0, stream>>>(hbuf, SC1, SH1, NN*64);
  if(store_t2){
    edge_gemm1_k<true><<<1250, 256, 0, stream>>>(hbuf, escr, edcr, w6p, b6, t2p, eS2, eQ2);
    bn_finalize_k<<<1, 256, 0, stream>>>(eS2, eQ2, (float)NE, w7, b7, nullptr, SC2, SH2, 256);
    edge_gemm2_k<<<5000, 256, 0, stream>>>(t2p, eids, SC2, SH2, w8p, b8, outp);
  } else {
    edge_gemm1_k<false><<<1250, 256, 0, stream>>>(hbuf, escr, edcr, w6p, b6, nullptr, eS2, eQ2);
    bn_finalize_k<<<1, 256, 0, stream>>>(eS2, eQ2, (float)NE, w7, b7, nullptr, SC2, SH2, 256);
    edge_fused_k<<<5000, 256, 0, stream>>>(hbuf, escr, edcr, eids, w6p, b6, SC2, SH2, w8p, b8, outp);
  }
}